// Round 4
// baseline (1643.585 us; speedup 1.0000x reference)
//
#include <hip/hip_runtime.h>
#include <hip/hip_bf16.h>

// ---------------------------------------------------------------------------
// Mamba2 mixer forward on MI355X (gfx950).
// HID=2048 DSTATE=128 K=4 DIN=4096 HDIM=64 NH=64 CHUNK=256, B=2 L=4096
//
// Precision plan (absmax budget 0.108, ref fp32):
//   - B, C, dt computed at ~fp32 precision via split-bf16 MFMA
//     (hi/lo decomposition, 3-term product: rel err ~2^-17).
//   - ssd_y: W=CB*Lmat and C*exp(Acs) rounded to bf16 AFTER fp32 sums, then
//     bf16 MFMA (one rounding, not amplified). x path bf16 throughout.
//   - GEMM operands (hs, w1 z/x rows, wo) pre-cast to bf16 once.
//
// R4 change: ssd_y rebuilt (was 348us at MfmaUtil 2.9% / VALU 14% --
// latency-bound on 134M exp + strided cbt loads):
//   - off-diagonal decay factorized e^{al-as} = e^{al-m}*e^{m-as}:
//     per-phase 64-entry q[] in LDS + 1 exp/thread; no per-element exp.
//   - masked diagonal built cooperatively by all 4 waves (16 exp/thread).
//   - waves below the diagonal skip cbt loads AND MFMA (were all-zero).
//   - Yo C-loads made coalesced (cooperative row/colgroup mapping + ea_s).
// cb_kernel split in l (grid 128->256 blocks; was using half the CUs).
// ---------------------------------------------------------------------------

typedef __bf16 v8bf __attribute__((ext_vector_type(8)));
typedef float  v4f  __attribute__((ext_vector_type(4)));

#define LL long long

__device__ inline v8bf load8(const float* p) {
    v4f a = *(const v4f*)p, b = *(const v4f*)(p + 4);
    v8bf r;
#pragma unroll
    for (int i = 0; i < 4; ++i) { r[i] = (__bf16)a[i]; r[i + 4] = (__bf16)b[i]; }
    return r;
}

__device__ __forceinline__ void gload_lds16(const __bf16* g, __bf16* l) {
    __builtin_amdgcn_global_load_lds(
        (const __attribute__((address_space(1))) void*)g,
        (__attribute__((address_space(3))) void*)l, 16, 0, 0);
}

// ---------------- fp32 -> bf16 cast (memory-bound, vectorized) ---------------
__global__ __launch_bounds__(256) void cast_bf16_kernel(
    const float* __restrict__ in, __bf16* __restrict__ out)
{
    LL i = ((LL)blockIdx.x * 256 + threadIdx.x) * 8;
    *(v8bf*)&out[i] = load8(&in[i]);
}

// ---------------- fp32 -> bf16 hi/lo split cast ------------------------------
__global__ __launch_bounds__(256) void cast_split_kernel(
    const float* __restrict__ in, __bf16* __restrict__ hi,
    __bf16* __restrict__ lo)
{
    LL i = ((LL)blockIdx.x * 256 + threadIdx.x) * 8;
    v4f a = *(const v4f*)&in[i], b = *(const v4f*)&in[i + 4];
    v8bf h, l;
#pragma unroll
    for (int k = 0; k < 4; ++k) {
        __bf16 hh = (__bf16)a[k];  h[k]     = hh;  l[k]     = (__bf16)(a[k] - (float)hh);
        __bf16 hb = (__bf16)b[k];  h[k + 4] = hb;  l[k + 4] = (__bf16)(b[k] - (float)hb);
    }
    *(v8bf*)&hi[i] = h;
    *(v8bf*)&lo[i] = l;
}

// ---------------- 256x256 8-phase bf16 GEMM:  C[M,N] = A[M,K]*B[N,K]^T ------
template <int MODE, int TM, int TN, int RN>
__global__ __launch_bounds__(512, 2) void gemm_bt_8p(
    const __bf16* __restrict__ Ab, const __bf16* __restrict__ Bb, int KT,
    int lda, int ldb,
    __bf16* __restrict__ z_out, __bf16* __restrict__ x_out,
    float* __restrict__ outf, int ldc)
{
    __shared__ __align__(16) __bf16 lds[65536];      // 128 KiB
    constexpr int RM = 8 / RN;
    constexpr int LM = TM / RM, LN = TN / RN;
    // 2D XCD-chunked swizzle: XCD x owns an LM x LN tile region.
    const int orig = blockIdx.x;
    const int x = orig & 7, loc = orig >> 3;
    const int M0 = ((x / RN) * LM + loc / LN) * 256;
    const int N0 = ((x % RN) * LN + loc % LN) * 256;

    const int tid  = threadIdx.x;
    const int lane = tid & 63, wave = tid >> 6;
    const int wr = wave >> 2, wc = wave & 3;         // 2x4 wave grid
    const int lrow = lane & 15, quad = lane >> 4;
    const int row0 = tid >> 3;                       // staging row 0..63
    const int g0   = (tid & 7) ^ (row0 & 7);         // inverse-swizzled chunk

    v4f acc[8][4] = {};
    v8bf aF[2][4], b0F[2][2], b1F[2][2];

#define STAGE_A(par, half, kt) do { \
    const __bf16* _s = Ab + (size_t)(M0 + (half)*128 + row0) * lda + (kt)*64 + g0*8; \
    __bf16* _d = lds + ((par)*2 + (half)) * 8192 + wave * 512; \
    gload_lds16(_s, _d); \
    gload_lds16(_s + (size_t)64 * lda, _d + 4096); \
} while (0)

#define STAGE_B(par, half, kt) do { \
    const __bf16* _s = Bb + (size_t)(N0 + (half)*128 + row0) * ldb + (kt)*64 + g0*8; \
    __bf16* _d = lds + 32768 + ((par)*2 + (half)) * 8192 + wave * 512; \
    gload_lds16(_s, _d); \
    gload_lds16(_s + (size_t)64 * ldb, _d + 4096); \
} while (0)

#define READ_A(par, qm) do { \
    const __bf16* _s = lds + ((par)*2 + wr) * 8192; \
    _Pragma("unroll") \
    for (int _ks = 0; _ks < 2; ++_ks) \
      _Pragma("unroll") \
      for (int _m = 0; _m < 4; ++_m) \
        aF[_ks][_m] = *(const v8bf*)&_s[((qm)*64 + _m*16 + lrow)*64 + \
                                        ((((_ks<<2)+quad) ^ (lrow&7))<<3)]; \
} while (0)

#define READ_B(par, qn, DST) do { \
    const __bf16* _s = lds + 32768 + ((par)*2 + (wc>>1)) * 8192; \
    _Pragma("unroll") \
    for (int _ks = 0; _ks < 2; ++_ks) \
      _Pragma("unroll") \
      for (int _n = 0; _n < 2; ++_n) \
        DST[_ks][_n] = *(const v8bf*)&_s[((wc&1)*64 + (qn)*32 + _n*16 + lrow)*64 + \
                                         ((((_ks<<2)+quad) ^ (lrow&7))<<3)]; \
} while (0)

#define MFQ(qm, qn, BF) do { \
    __builtin_amdgcn_s_setprio(1); \
    _Pragma("unroll") \
    for (int _ks = 0; _ks < 2; ++_ks) \
      _Pragma("unroll") \
      for (int _m = 0; _m < 4; ++_m) \
        _Pragma("unroll") \
        for (int _n = 0; _n < 2; ++_n) \
          acc[(qm)*4+_m][(qn)*2+_n] = __builtin_amdgcn_mfma_f32_16x16x32_bf16( \
              aF[_ks][_m], BF[_ks][_n], acc[(qm)*4+_m][(qn)*2+_n], 0, 0, 0); \
    __builtin_amdgcn_s_setprio(0); \
} while (0)

#define PBAR  __builtin_amdgcn_s_barrier()
#define LGKM0 asm volatile("s_waitcnt lgkmcnt(0)" ::: "memory")
#define VMC4  asm volatile("s_waitcnt vmcnt(4)" ::: "memory")
#define VMC0  asm volatile("s_waitcnt vmcnt(0)" ::: "memory")

    // ---- prologue: tile0 all four halves + tile1.{A0,B0}
    STAGE_A(0, 0, 0); STAGE_A(0, 1, 0); STAGE_B(0, 0, 0); STAGE_B(0, 1, 0);
    STAGE_A(1, 0, 1); STAGE_B(1, 0, 1);
    VMC4; PBAR;

    const int KT2 = KT >> 1;
    for (int it = 0; it < KT2; ++it) {
        const int T0 = 2 * it, T1 = 2 * it + 1;
        const bool notlast = (it < KT2 - 1);
        // P1
        READ_A(0, 0); READ_B(0, 0, b0F);
        STAGE_A(1, 1, T1);
        PBAR; LGKM0; MFQ(0, 0, b0F); PBAR;
        // P2
        READ_B(0, 1, b1F);
        STAGE_B(1, 1, T1);
        PBAR; LGKM0; MFQ(0, 1, b1F); PBAR;
        // P3
        READ_A(0, 1);
        if (notlast) STAGE_B(0, 0, T0 + 2);
        PBAR; LGKM0; MFQ(1, 0, b0F); PBAR;
        // P4
        if (notlast) STAGE_A(0, 0, T0 + 2);
        PBAR; LGKM0; MFQ(1, 1, b1F);
        if (notlast) { VMC4; } else { VMC0; }
        PBAR;
        // P5
        READ_A(1, 0); READ_B(1, 0, b0F);
        if (notlast) STAGE_A(0, 1, T0 + 2);
        PBAR; LGKM0; MFQ(0, 0, b0F); PBAR;
        // P6
        READ_B(1, 1, b1F);
        if (notlast) STAGE_B(0, 1, T0 + 2);
        PBAR; LGKM0; MFQ(0, 1, b1F); PBAR;
        // P7
        READ_A(1, 1);
        if (notlast) STAGE_B(1, 0, T1 + 2);
        PBAR; LGKM0; MFQ(1, 0, b0F); PBAR;
        // P8
        if (notlast) STAGE_A(1, 0, T1 + 2);
        PBAR; LGKM0; MFQ(1, 1, b1F);
        if (notlast) { VMC4; } else { VMC0; }
        PBAR;
    }

#undef STAGE_A
#undef STAGE_B
#undef READ_A
#undef READ_B
#undef MFQ

    // ---- epilogue: wave (wr,wc) owns rows [wr*128,+128), cols [wc*64,+64)
#pragma unroll
    for (int m = 0; m < 8; ++m)
#pragma unroll
        for (int n = 0; n < 4; ++n)
#pragma unroll
            for (int r = 0; r < 4; ++r) {
                int row = M0 + wr * 128 + m * 16 + quad * 4 + r;
                int col = N0 + wc * 64 + n * 16 + lrow;
                float v = acc[m][n][r];
                if constexpr (MODE == 1) {
                    if (col < 4096) z_out[(LL)row * 4096 + col] = (__bf16)v;
                    else            x_out[(LL)row * 4096 + (col - 4096)] = (__bf16)v;
                } else {
                    outf[(LL)row * ldc + col] = v;
                }
            }
}

// ---------------- B/C/dt strip GEMM via split-bf16 MFMA ----------------------
__global__ __launch_bounds__(256) void bcdt_gemm_kernel(
    const __bf16* __restrict__ Ahi, const __bf16* __restrict__ Alo,
    const __bf16* __restrict__ Whi, const __bf16* __restrict__ Wlo,
    const float* __restrict__ dtbi,
    float* __restrict__ bcr, float* __restrict__ dt)
{
    __shared__ __align__(16) __bf16 sAh[128 * 64];
    __shared__ __align__(16) __bf16 sAl[128 * 64];
    __shared__ __align__(16) __bf16 sWh[64 * 64];
    __shared__ __align__(16) __bf16 sWl[64 * 64];
    const int orig = blockIdx.x;
    const int swz = (orig & 7) * 40 + (orig >> 3);
    const int m0 = (swz / 5) * 128;
    const int n0 = (swz % 5) * 64;
    const int tid = threadIdx.x;
    const int lane = tid & 63, wave = tid >> 6;
    const int lrow = lane & 15, quad = lane >> 4;
    const int wm = wave * 32;
    v4f acc[2][4] = {};

    for (int k0 = 0; k0 < 2048; k0 += 64) {
#pragma unroll
        for (int i = 0; i < 4; ++i) {
            int e = tid + i * 256;
            int row = e >> 3, g = (e & 7) ^ (row & 7);
            const LL so = (LL)(m0 + row) * 2048 + k0 + g * 8;
            gload_lds16(&Ahi[so], &sAh[wave * 512 + i * 2048]);
            gload_lds16(&Alo[so], &sAl[wave * 512 + i * 2048]);
        }
#pragma unroll
        for (int i = 0; i < 2; ++i) {
            int e = tid + i * 256;
            int row = e >> 3, g = (e & 7) ^ (row & 7);
            const LL so = (LL)(n0 + row) * 2048 + k0 + g * 8;
            gload_lds16(&Whi[so], &sWh[wave * 512 + i * 2048]);
            gload_lds16(&Wlo[so], &sWl[wave * 512 + i * 2048]);
        }
        __syncthreads();
#pragma unroll
        for (int ks = 0; ks < 2; ++ks) {
            v8bf ah[2], al[2], wh[4], wl[4];
#pragma unroll
            for (int i = 0; i < 2; ++i) {
                int r = wm + i * 16 + lrow;
                int c = ((((ks << 2) + quad) ^ (lrow & 7)) << 3);
                ah[i] = *(const v8bf*)&sAh[r * 64 + c];
                al[i] = *(const v8bf*)&sAl[r * 64 + c];
            }
#pragma unroll
            for (int j = 0; j < 4; ++j) {
                int r = j * 16 + lrow;
                int c = ((((ks << 2) + quad) ^ (lrow & 7)) << 3);
                wh[j] = *(const v8bf*)&sWh[r * 64 + c];
                wl[j] = *(const v8bf*)&sWl[r * 64 + c];
            }
#pragma unroll
            for (int i = 0; i < 2; ++i)
#pragma unroll
                for (int j = 0; j < 4; ++j) {
                    acc[i][j] = __builtin_amdgcn_mfma_f32_16x16x32_bf16(ah[i], wh[j], acc[i][j], 0, 0, 0);
                    acc[i][j] = __builtin_amdgcn_mfma_f32_16x16x32_bf16(ah[i], wl[j], acc[i][j], 0, 0, 0);
                    acc[i][j] = __builtin_amdgcn_mfma_f32_16x16x32_bf16(al[i], wh[j], acc[i][j], 0, 0, 0);
                }
        }
        __syncthreads();
    }
#pragma unroll
    for (int i = 0; i < 2; ++i)
#pragma unroll
        for (int j = 0; j < 4; ++j)
#pragma unroll
            for (int r = 0; r < 4; ++r) {
                int row = m0 + wm + i * 16 + quad * 4 + r;
                int sc = n0 + j * 16 + lrow;
                float v = acc[i][j][r];
                if (sc < 256) {
                    bcr[(LL)row * 256 + sc] = v;
                } else {
                    float x = v + dtbi[sc - 256];
                    dt[row * 64 + (sc - 256)] = (x > 20.f) ? x : log1pf(__expf(x));
                }
            }
}

// ---------------- causal conv1d (K=4) + SiLU, x channels (bf16) --------------
__global__ __launch_bounds__(256) void conv_x_kernel(
    const __bf16* __restrict__ xp, const float* __restrict__ cw,
    const float* __restrict__ cbias, __bf16* __restrict__ xq)
{
    int ch = blockIdx.x * 256 + threadIdx.x;
    int l = blockIdx.y, b = blockIdx.z;
    float acc = cbias[ch];
#pragma unroll
    for (int i = 0; i < 4; ++i) {
        int ls = l - 3 + i;
        if (ls >= 0)
            acc += (float)xp[((LL)b * 4096 + ls) * 4096 + ch] * cw[ch * 4 + i];
    }
    acc = acc / (1.f + __expf(-acc));
    xq[((LL)b * 4096 + l) * 4096 + ch] = (__bf16)acc;
}

// ---------------- causal conv1d (K=4) + SiLU, B/C channels (fp32) ------------
__global__ __launch_bounds__(256) void conv_bc_kernel(
    const float* __restrict__ bcr, const float* __restrict__ cw,
    const float* __restrict__ cbias, float* __restrict__ bcc)
{
    int ch = threadIdx.x;
    int l = blockIdx.y, b = blockIdx.z;
    float acc = cbias[4096 + ch];
#pragma unroll
    for (int i = 0; i < 4; ++i) {
        int ls = l - 3 + i;
        if (ls >= 0)
            acc += bcr[((LL)b * 4096 + ls) * 256 + ch] * cw[(4096 + ch) * 4 + i];
    }
    acc = acc / (1.f + __expf(-acc));
    bcc[((LL)b * 4096 + l) * 256 + ch] = acc;
}

// ---------------- per-chunk inclusive cumsum of dA = dt*A --------------------
__global__ __launch_bounds__(256) void cumsum_kernel(
    const float* __restrict__ dt, const float* __restrict__ alog,
    float* __restrict__ acs, float* __restrict__ cdec)
{
    int h = blockIdx.x, c = blockIdx.y, b = blockIdx.z;
    int s = threadIdx.x;
    __shared__ float buf[256];
    float Av = -expf(alog[h]);
    int bl = b * 4096 + c * 256 + s;
    buf[s] = dt[bl * 64 + h] * Av;
    __syncthreads();
    for (int off = 1; off < 256; off <<= 1) {
        float v = (s >= off) ? buf[s - off] : 0.f;
        __syncthreads();
        buf[s] += v;
        __syncthreads();
    }
    int abase = (((b * 16) + c) * 64 + h) * 256;
    acs[abase + s] = buf[s];
    if (s == 255) cdec[(b * 64 + h) * 16 + c] = expf(buf[s]);
}

// ---------------- chunk states: cs[b,c,h,p,n] = sum_s B[s,n]*dec[s]*x[s,p]*dt[s]
__global__ __launch_bounds__(256) void chunk_state_kernel(
    const __bf16* __restrict__ xq, const float* __restrict__ bcc,
    const float* __restrict__ dtb, const float* __restrict__ acs,
    float* __restrict__ cs)
{
    int h = blockIdx.x, c = blockIdx.y, b = blockIdx.z;
    int t = threadIdx.x;
    int lg = t & 63, pg = t >> 6;
    int n0 = lg * 2;
    __shared__ __align__(16) float xdt_s[64 * 68];
    __shared__ float dec_s[64];
    const LL lbase = (LL)b * 4096 + c * 256;
    const int abase = (((b * 16) + c) * 64 + h) * 256;
    float alast = acs[abase + 255];
    float a0[16] = {}, a1[16] = {};
    for (int st = 0; st < 4; ++st) {
        for (int i = 0; i < 16; ++i) {
            int e = t + i * 256; int sp = e >> 6, p = e & 63;
            LL row = lbase + st * 64 + sp;
            xdt_s[sp * 68 + p] = (float)xq[row * 4096 + h * 64 + p] * dtb[(row << 6) + h];
        }
        if (t < 64) dec_s[t] = __expf(alast - acs[abase + st * 64 + t]);
        __syncthreads();
        for (int sp = 0; sp < 64; ++sp) {
            LL row = lbase + st * 64 + sp;
            float2 bb = *(const float2*)&bcc[row * 256 + n0];
            float dd = dec_s[sp];
            float b0 = bb.x * dd, b1 = bb.y * dd;
#pragma unroll
            for (int q = 0; q < 4; ++q) {
                v4f xv = *(const v4f*)&xdt_s[sp * 68 + pg * 16 + q * 4];
#pragma unroll
                for (int j = 0; j < 4; ++j) { a0[q * 4 + j] += b0 * xv[j]; a1[q * 4 + j] += b1 * xv[j]; }
            }
        }
        __syncthreads();
    }
    const LL obase = ((LL)(((b * 16) + c) * 64 + h)) * 8192;
    for (int pp = 0; pp < 16; ++pp) {
        int p = pg * 16 + pp;
        cs[obase + p * 128 + n0]     = a0[pp];
        cs[obase + p * 128 + n0 + 1] = a1[pp];
    }
}

// ---------------- sequential scan over 16 chunks (IN PLACE: cs -> prev) ------
__global__ __launch_bounds__(256) void scan_kernel(
    float* __restrict__ cs, const float* __restrict__ cdec)
{
    int h = blockIdx.x, b = blockIdx.y;
    int t = threadIdx.x;
    float st[32];
#pragma unroll
    for (int i = 0; i < 32; ++i) st[i] = 0.f;
    for (int c = 0; c < 16; ++c) {
        LL base = ((LL)(((b * 16) + c) * 64 + h)) * 8192;
        float cd = cdec[(b * 64 + h) * 16 + c];
#pragma unroll
        for (int i = 0; i < 32; ++i) {
            int e = i * 256 + t;
            float v = cs[base + e];
            cs[base + e] = st[i];
            st[i] = st[i] * cd + v;
        }
    }
}

// ---------------- CBT[b,c,s,l] = sum_n B[s,n]*C[l,n]  ------------------------
// l-split: grid.x = 8 -> (st = x&3, lh = x>>2); each block: 64 s x 128 l.
__global__ __launch_bounds__(256) void cb_kernel(const float* __restrict__ bcc,
                                                 float* __restrict__ cbt)
{
    int bx = blockIdx.x;
    int st = bx & 3, lh = bx >> 2;
    int c = blockIdx.y, b = blockIdx.z;
    int t = threadIdx.x;
    int lg = t & 63, pg = t >> 6;
    __shared__ float cr_s[128 * 33];
    __shared__ __align__(16) float brT[32 * 68];
    const LL lbase = (LL)b * 4096 + c * 256;
    const int l0 = lh * 128;
    float acc[2][16] = {};
    for (int nt = 0; nt < 4; ++nt) {
        for (int i = 0; i < 16; ++i) {
            int e = t + i * 256; int l = e >> 5, np = e & 31;
            cr_s[l * 33 + np] = bcc[(lbase + l0 + l) * 256 + 128 + nt * 32 + np];
        }
        for (int i = 0; i < 8; ++i) {
            int e = t + i * 256; int sp = e >> 5, np = e & 31;
            brT[np * 68 + sp] = bcc[(lbase + st * 64 + sp) * 256 + nt * 32 + np];
        }
        __syncthreads();
        for (int np = 0; np < 32; ++np) {
            float w0 = cr_s[lg * 33 + np], w1 = cr_s[(lg + 64) * 33 + np];
#pragma unroll
            for (int q = 0; q < 4; ++q) {
                v4f bv = *(const v4f*)&brT[np * 68 + pg * 16 + q * 4];
#pragma unroll
                for (int j = 0; j < 4; ++j) {
                    acc[0][q * 4 + j] += w0 * bv[j];
                    acc[1][q * 4 + j] += w1 * bv[j];
                }
            }
        }
        __syncthreads();
    }
    const LL obase = ((LL)((b * 16) + c)) * 65536;
#pragma unroll
    for (int r = 0; r < 2; ++r)
        for (int sp = 0; sp < 16; ++sp) {
            int s = st * 64 + pg * 16 + sp;
            cbt[obase + (LL)s * 256 + (l0 + lg + r * 64)] = acc[r][sp];
        }
}

// ---------------- SSD output via MFMA: Y[256,64] = A[256,384]·Bm[384,64] -----
// Phase kb<4 (Yd): A[l][s] = CB[s,l]*exp(acs[l]-acs[s])*1[s<=l].
//   off-diag (wave>kb): exp factorized: r[l]*q[s], q in LDS (64 exps/phase).
//   diag (rows of wave kb): built cooperatively by all 4 waves, masked exp.
//   waves<kb: skip (A rows all zero -> skip loads AND MFMA).
// Phase kb>=4 (Yo): A = C*exp(acs[l]) (coalesced coop build), B = prev.
__global__ __launch_bounds__(256) void ssd_y_kernel(
    __bf16* __restrict__ xq, const float* __restrict__ bcc,
    const float* __restrict__ dtb, const float* __restrict__ acs,
    const float* __restrict__ cbt, const float* __restrict__ prevS,
    const float* __restrict__ Dv)
{
    const int h = blockIdx.x, c = blockIdx.y, b = blockIdx.z;
    const int t = threadIdx.x;
    const int lane = t & 63, wave = t >> 6;
    const int lrow = lane & 15, quad = lane >> 4;
    const int wm = wave * 64;
    __shared__ __align__(16) __bf16 As[256][72];     // rows l, 64 k (+8 pad)
    __shared__ __align__(16) __bf16 Bs[64 * 64];     // swizzled [p][k]
    __shared__ float acs_s[256];
    __shared__ float ea_s[256];
    __shared__ float qbuf[64];
    const LL lbase = (LL)b * 4096 + c * 256;
    const int abase = (((b * 16) + c) * 64 + h) * 256;
    acs_s[t] = acs[abase + t];
    const float acl_t = acs_s[t];                    // own value
    ea_s[t] = __expf(acl_t);
    __syncthreads();
    const LL cbbase = ((LL)((b * 16) + c)) * 65536;
    const LL pbase  = ((LL)(((b * 16) + c) * 64 + h)) * 8192;
    v4f acc[4][4] = {};

    for (int kb = 0; kb < 6; ++kb) {
        // ======== cooperative slot ========
        if (kb < 4) {
            const int sb = kb * 64;
            // q[s'] = exp(m - acs[sb+s']), m = acs[sb+63]  (<=1, exact factor)
            if (t < 64) qbuf[t] = __expf(acs_s[sb + 63] - acs_s[sb + t]);
            // diagonal rows sb..sb+63 built by ALL waves (load-balanced):
            // wave w -> rows sb+16w+lrow, cols quad*16..+15
            {
                const int row = sb + wave * 16 + lrow;
                const int c0 = quad * 16;
                const float al = acs_s[row];
                v8bf wv0, wv1;
#pragma unroll
                for (int j = 0; j < 8; ++j) {
                    int s0 = sb + c0 + j;
                    int s1 = s0 + 8;
                    float cb0 = cbt[cbbase + (LL)s0 * 256 + row];
                    float cb1 = cbt[cbbase + (LL)s1 * 256 + row];
                    wv0[j] = (__bf16)((s0 <= row) ? cb0 * __expf(al - acs_s[s0]) : 0.f);
                    wv1[j] = (__bf16)((s1 <= row) ? cb1 * __expf(al - acs_s[s1]) : 0.f);
                }
                *(v8bf*)&As[row][c0]     = wv0;
                *(v8bf*)&As[row][c0 + 8] = wv1;
            }
            // B tile: xdt, swizzled [p][s]
#pragma unroll
            for (int i = 0; i < 16; ++i) {
                int e = t + i * 256; int p = e & 63, sp = e >> 6;
                LL row = lbase + sb + sp;
                float xv = (float)xq[row * 4096 + h * 64 + p] * dtb[((int)row) * 64 + h];
                Bs[p * 64 + ((((sp >> 3) ^ (p & 7)) << 3) | (sp & 7))] = (__bf16)xv;
            }
        } else {
            const int nb = (kb - 4) * 64;
            // A = C * exp(acs[l]), coalesced cooperative build
#pragma unroll
            for (int i = 0; i < 8; ++i) {
                int e = t + i * 256;
                int l = e >> 3, g = e & 7;
                const LL cb0 = (lbase + l) * 256 + 128 + nb + g * 8;
                v4f c0 = *(const v4f*)&bcc[cb0];
                v4f c1 = *(const v4f*)&bcc[cb0 + 4];
                float ea = ea_s[l];
                v8bf wv;
#pragma unroll
                for (int u = 0; u < 4; ++u) {
                    wv[u]     = (__bf16)(c0[u] * ea);
                    wv[u + 4] = (__bf16)(c1[u] * ea);
                }
                *(v8bf*)&As[l][g * 8] = wv;
            }
            // B tile: prev states
#pragma unroll
            for (int i = 0; i < 16; ++i) {
                int e = t + i * 256; int n = e & 63, p = e >> 6;
                float pv = prevS[pbase + (LL)p * 128 + nb + n];
                Bs[p * 64 + ((((n >> 3) ^ (p & 7)) << 3) | (n & 7))] = (__bf16)pv;
            }
        }
        __syncthreads();
        // ======== per-wave slot ========
        if (kb < 4 && wave > kb) {
            // off-diagonal factorized rows (thread t owns row t; same-wave use)
            const int sb = kb * 64;
            const float r = __expf(acl_t - acs_s[sb + 63]);   // <= 1
#pragma unroll
            for (int g = 0; g < 8; ++g) {
                v4f q0 = *(const v4f*)&qbuf[g * 8];
                v4f q1 = *(const v4f*)&qbuf[g * 8 + 4];
                v8bf wv;
#pragma unroll
                for (int u = 0; u < 4; ++u) {
                    float cbv0 = cbt[cbbase + (LL)(sb + g * 8 + u) * 256 + t];
                    float cbv1 = cbt[cbbase + (LL)(sb + g * 8 + 4 + u) * 256 + t];
                    wv[u]     = (__bf16)(cbv0 * (r * q0[u]));
                    wv[u + 4] = (__bf16)(cbv1 * (r * q1[u]));
                }
                *(v8bf*)&As[t][g * 8] = wv;
            }
            asm volatile("s_waitcnt lgkmcnt(0)" ::: "memory");
            __builtin_amdgcn_sched_barrier(0);
        }
        if (kb >= 4 || wave >= kb) {
            // MFMA: 2 ksteps of 32 (waves below diagonal skip — A is zero)
#pragma unroll
            for (int ks = 0; ks < 2; ++ks) {
                v8bf af[4], bfv[4];
#pragma unroll
                for (int i = 0; i < 4; ++i)
                    af[i] = *(const v8bf*)&As[wm + i * 16 + lrow][ks * 32 + quad * 8];
#pragma unroll
                for (int j = 0; j < 4; ++j) {
                    int p = j * 16 + lrow;
                    int kg = (ks * 4 + quad) ^ (p & 7);
                    bfv[j] = *(const v8bf*)&Bs[p * 64 + kg * 8];
                }
#pragma unroll
                for (int i = 0; i < 4; ++i)
#pragma unroll
                    for (int j = 0; j < 4; ++j)
                        acc[i][j] = __builtin_amdgcn_mfma_f32_16x16x32_bf16(af[i], bfv[j], acc[i][j], 0, 0, 0);
            }
        }
        __syncthreads();
    }
    // ---- epilogue: + D*x, write Y over x region (owner lane reads own cell)
    const float Dh = Dv[h];
#pragma unroll
    for (int i = 0; i < 4; ++i)
#pragma unroll
        for (int j = 0; j < 4; ++j)
#pragma unroll
            for (int r = 0; r < 4; ++r) {
                int l = wm + i * 16 + quad * 4 + r;
                int p = j * 16 + lrow;
                LL idx = (lbase + l) * 4096 + h * 64 + p;
                float v = acc[i][j][r] + Dh * (float)xq[idx];
                xq[idx] = (__bf16)v;
            }
}

// ---------------- gated RMSNorm (in-place on xq, stride 4096) ----------------
__global__ __launch_bounds__(256) void rmsnorm_kernel(
    __bf16* __restrict__ y, const __bf16* __restrict__ z,
    const float* __restrict__ nw)
{
    LL r = blockIdx.x;
    int t = threadIdx.x;
    float vals[16]; float ss = 0.f;
#pragma unroll
    for (int i = 0; i < 16; ++i) {
        int j = i * 256 + t;
        float yv = (float)y[r * 4096 + j];
        float zv = (float)z[r * 4096 + j];
        float v = yv * (zv / (1.f + __expf(-zv)));
        vals[i] = v; ss += v * v;
    }
#pragma unroll
    for (int off = 32; off >= 1; off >>= 1) ss += __shfl_down(ss, off, 64);
    __shared__ float red[4];
    if ((t & 63) == 0) red[t >> 6] = ss;
    __syncthreads();
    float tot = red[0] + red[1] + red[2] + red[3];
    float rstd = rsqrtf(tot * (1.f / 4096.f) + 1e-5f);
#pragma unroll
    for (int i = 0; i < 16; ++i) {
        int j = i * 256 + t;
        y[r * 4096 + j] = (__bf16)(vals[i] * rstd * nw[j]);
    }
}

// ---------------------------------------------------------------------------
extern "C" void kernel_launch(void* const* d_in, const int* in_sizes, int n_in,
                              void* d_out, int out_size, void* d_ws, size_t ws_size,
                              hipStream_t stream) {
    const float* hs    = (const float*)d_in[0];
    const float* w1    = (const float*)d_in[1];
    const float* cw    = (const float*)d_in[2];
    const float* cbias = (const float*)d_in[3];
    const float* dtbi  = (const float*)d_in[4];
    const float* alog  = (const float*)d_in[5];
    const float* Dv    = (const float*)d_in[6];
    const float* nw    = (const float*)d_in[7];
    const float* wo    = (const float*)d_in[8];
    float* out = (float*)d_out;
    (void)in_sizes; (void)n_in; (void)out_size; (void)ws_size;

    char* ws = (char*)d_ws;
    size_t off = 0;
    auto alloc = [&](size_t bytes) { void* p = ws + off; off += (bytes + 255) & ~(size_t)255; return p; };
    __bf16* xp_b  = (__bf16*)alloc((size_t)8192 * 4096 * 2);
    __bf16* xq_b  = (__bf16*)alloc((size_t)8192 * 4096 * 2);
    float*  bcr_f = (float*) alloc((size_t)8192 * 256 * 4);
    float*  bcc_f = (float*) alloc((size_t)8192 * 256 * 4);
    float*  dt_f  = (float*) alloc((size_t)8192 * 64 * 4);
    float*  acs_f = (float*) alloc((size_t)2 * 16 * 64 * 256 * 4);
    float*  cd_f  = (float*) alloc((size_t)2 * 64 * 16 * 4);
    float*  cbt_f = (float*) alloc((size_t)2 * 16 * 256 * 256 * 4);
    float*  cs_f  = (float*)xp_b;           // aliases xp_b AFTER conv_x
    __bf16* z_b   = (__bf16*)d_out;

    __bf16* hs_b  = xq_b;                          // 8192*2048 bf16 = 32 MiB
    __bf16* w1_b  = xq_b + (size_t)8192 * 2048;    // 8192*2048 bf16 = 32 MiB
    __bf16* hs_lo = (__bf16*)xp_b;                 // 8192*2048 bf16 = 32 MiB
    __bf16* ws_hi = hs_lo + (size_t)8192 * 2048;   // 320*2048 bf16
    __bf16* ws_lo = ws_hi + (size_t)320 * 2048;    // 320*2048 bf16
    __bf16* wo_b  = (__bf16*)xp_b;                 // 2048*4096 bf16 = 16 MiB

    cast_split_kernel<<<8192, 256, 0, stream>>>(hs, hs_b, hs_lo);
    cast_bf16_kernel<<<8192, 256, 0, stream>>>(w1, w1_b);   // rows 0..8191
    cast_split_kernel<<<320, 256, 0, stream>>>(w1 + (size_t)8192 * 2048, ws_hi, ws_lo);
    // B/C/dt strip (reads xp_b aliases) BEFORE gemm1 overwrites xp_b
    bcdt_gemm_kernel<<<320, 256, 0, stream>>>(hs_b, hs_lo, ws_hi, ws_lo,
                                              dtbi, bcr_f, dt_f);
    // GEMM1: M=8192 N=8192 K=2048 -> 32x32 tiles, XCD regions 16x8
    gemm_bt_8p<1, 32, 32, 4><<<dim3(1024), 512, 0, stream>>>(
        hs_b, w1_b, 32, 2048, 2048, z_b, xp_b, nullptr, 0);
    conv_x_kernel<<<dim3(16, 4096, 2), 256, 0, stream>>>(xp_b, cw, cbias, xq_b);
    conv_bc_kernel<<<dim3(1, 4096, 2), 256, 0, stream>>>(bcr_f, cw, cbias, bcc_f);
    cumsum_kernel<<<dim3(64, 16, 2), 256, 0, stream>>>(dt_f, alog, acs_f, cd_f);
    chunk_state_kernel<<<dim3(64, 16, 2), 256, 0, stream>>>(xq_b, bcc_f, dt_f, acs_f, cs_f);
    scan_kernel<<<dim3(64, 2), 256, 0, stream>>>(cs_f, cd_f);
    cb_kernel<<<dim3(8, 16, 2), 256, 0, stream>>>(bcc_f, cbt_f);
    ssd_y_kernel<<<dim3(64, 16, 2), 256, 0, stream>>>(xq_b, bcc_f, dt_f, acs_f, cbt_f, cs_f, Dv);
    cast_bf16_kernel<<<4096, 256, 0, stream>>>(wo, wo_b);   // 2048*4096
    rmsnorm_kernel<<<8192, 256, 0, stream>>>(xq_b, z_b, nw);
    // GEMM2: M=8192 N=2048 K=4096 -> 32x8 tiles, XCD regions 4x8
    gemm_bt_8p<2, 32, 8, 1><<<dim3(256), 512, 0, stream>>>(
        xq_b, wo_b, 64, 4096, 4096, nullptr, nullptr, out, 2048);
}

// Round 5
// 1457.867 us; speedup vs baseline: 1.1274x; 1.1274x over previous
//
#include <hip/hip_runtime.h>
#include <hip/hip_bf16.h>

// ---------------------------------------------------------------------------
// Mamba2 mixer forward on MI355X (gfx950).
// HID=2048 DSTATE=128 K=4 DIN=4096 HDIM=64 NH=64 CHUNK=256, B=2 L=4096
//
// Precision plan (absmax budget 0.108, ref fp32):
//   - B, C, dt computed at ~fp32 precision via split-bf16 MFMA
//     (hi/lo decomposition, 3-term product: rel err ~2^-17).
//   - ssd_y: W=CB*Lmat and C*exp(Acs) rounded to bf16 AFTER fp32 sums, then
//     bf16 MFMA (one rounding, not amplified). x path bf16 throughout.
//   - GEMM operands (hs, w1 z/x rows, wo) pre-cast to bf16 once.
//
// R5 change (post-mortem of R4's regression: VGPR 116->136 crossed the
// occupancy cliff, 22.7%->11.6%, latency-bound kernel lost its TLP):
// ssd_y = R3 skeleton (uniform thread-t-builds-row-t, one build/sync/MFMA/
// sync pair, 116 VGPR) + register-lean factorization:
//   - qbuf[4][64] = exp(m_kb - acs[s]) precomputed once (1 exp/thread, 1KB).
//   - phase kb < wave: entries = cbt * (r * q[kb][s]), r = 1 exp/phase.
//   - phase kb == wave: R3's masked per-element exp (64 exps).
//   - phase kb > wave: skip loads, writes AND MFMA (rows structurally zero).
// cb_kernel keeps R4's l-split (grid 256 blocks).
// ---------------------------------------------------------------------------

typedef __bf16 v8bf __attribute__((ext_vector_type(8)));
typedef float  v4f  __attribute__((ext_vector_type(4)));

#define LL long long

__device__ inline v8bf load8(const float* p) {
    v4f a = *(const v4f*)p, b = *(const v4f*)(p + 4);
    v8bf r;
#pragma unroll
    for (int i = 0; i < 4; ++i) { r[i] = (__bf16)a[i]; r[i + 4] = (__bf16)b[i]; }
    return r;
}

__device__ __forceinline__ void gload_lds16(const __bf16* g, __bf16* l) {
    __builtin_amdgcn_global_load_lds(
        (const __attribute__((address_space(1))) void*)g,
        (__attribute__((address_space(3))) void*)l, 16, 0, 0);
}

// ---------------- fp32 -> bf16 cast (memory-bound, vectorized) ---------------
__global__ __launch_bounds__(256) void cast_bf16_kernel(
    const float* __restrict__ in, __bf16* __restrict__ out)
{
    LL i = ((LL)blockIdx.x * 256 + threadIdx.x) * 8;
    *(v8bf*)&out[i] = load8(&in[i]);
}

// ---------------- fp32 -> bf16 hi/lo split cast ------------------------------
__global__ __launch_bounds__(256) void cast_split_kernel(
    const float* __restrict__ in, __bf16* __restrict__ hi,
    __bf16* __restrict__ lo)
{
    LL i = ((LL)blockIdx.x * 256 + threadIdx.x) * 8;
    v4f a = *(const v4f*)&in[i], b = *(const v4f*)&in[i + 4];
    v8bf h, l;
#pragma unroll
    for (int k = 0; k < 4; ++k) {
        __bf16 hh = (__bf16)a[k];  h[k]     = hh;  l[k]     = (__bf16)(a[k] - (float)hh);
        __bf16 hb = (__bf16)b[k];  h[k + 4] = hb;  l[k + 4] = (__bf16)(b[k] - (float)hb);
    }
    *(v8bf*)&hi[i] = h;
    *(v8bf*)&lo[i] = l;
}

// ---------------- 256x256 8-phase bf16 GEMM:  C[M,N] = A[M,K]*B[N,K]^T ------
template <int MODE, int TM, int TN, int RN>
__global__ __launch_bounds__(512, 2) void gemm_bt_8p(
    const __bf16* __restrict__ Ab, const __bf16* __restrict__ Bb, int KT,
    int lda, int ldb,
    __bf16* __restrict__ z_out, __bf16* __restrict__ x_out,
    float* __restrict__ outf, int ldc)
{
    __shared__ __align__(16) __bf16 lds[65536];      // 128 KiB
    constexpr int RM = 8 / RN;
    constexpr int LM = TM / RM, LN = TN / RN;
    // 2D XCD-chunked swizzle: XCD x owns an LM x LN tile region.
    const int orig = blockIdx.x;
    const int x = orig & 7, loc = orig >> 3;
    const int M0 = ((x / RN) * LM + loc / LN) * 256;
    const int N0 = ((x % RN) * LN + loc % LN) * 256;

    const int tid  = threadIdx.x;
    const int lane = tid & 63, wave = tid >> 6;
    const int wr = wave >> 2, wc = wave & 3;         // 2x4 wave grid
    const int lrow = lane & 15, quad = lane >> 4;
    const int row0 = tid >> 3;                       // staging row 0..63
    const int g0   = (tid & 7) ^ (row0 & 7);         // inverse-swizzled chunk

    v4f acc[8][4] = {};
    v8bf aF[2][4], b0F[2][2], b1F[2][2];

#define STAGE_A(par, half, kt) do { \
    const __bf16* _s = Ab + (size_t)(M0 + (half)*128 + row0) * lda + (kt)*64 + g0*8; \
    __bf16* _d = lds + ((par)*2 + (half)) * 8192 + wave * 512; \
    gload_lds16(_s, _d); \
    gload_lds16(_s + (size_t)64 * lda, _d + 4096); \
} while (0)

#define STAGE_B(par, half, kt) do { \
    const __bf16* _s = Bb + (size_t)(N0 + (half)*128 + row0) * ldb + (kt)*64 + g0*8; \
    __bf16* _d = lds + 32768 + ((par)*2 + (half)) * 8192 + wave * 512; \
    gload_lds16(_s, _d); \
    gload_lds16(_s + (size_t)64 * ldb, _d + 4096); \
} while (0)

#define READ_A(par, qm) do { \
    const __bf16* _s = lds + ((par)*2 + wr) * 8192; \
    _Pragma("unroll") \
    for (int _ks = 0; _ks < 2; ++_ks) \
      _Pragma("unroll") \
      for (int _m = 0; _m < 4; ++_m) \
        aF[_ks][_m] = *(const v8bf*)&_s[((qm)*64 + _m*16 + lrow)*64 + \
                                        ((((_ks<<2)+quad) ^ (lrow&7))<<3)]; \
} while (0)

#define READ_B(par, qn, DST) do { \
    const __bf16* _s = lds + 32768 + ((par)*2 + (wc>>1)) * 8192; \
    _Pragma("unroll") \
    for (int _ks = 0; _ks < 2; ++_ks) \
      _Pragma("unroll") \
      for (int _n = 0; _n < 2; ++_n) \
        DST[_ks][_n] = *(const v8bf*)&_s[((wc&1)*64 + (qn)*32 + _n*16 + lrow)*64 + \
                                         ((((_ks<<2)+quad) ^ (lrow&7))<<3)]; \
} while (0)

#define MFQ(qm, qn, BF) do { \
    __builtin_amdgcn_s_setprio(1); \
    _Pragma("unroll") \
    for (int _ks = 0; _ks < 2; ++_ks) \
      _Pragma("unroll") \
      for (int _m = 0; _m < 4; ++_m) \
        _Pragma("unroll") \
        for (int _n = 0; _n < 2; ++_n) \
          acc[(qm)*4+_m][(qn)*2+_n] = __builtin_amdgcn_mfma_f32_16x16x32_bf16( \
              aF[_ks][_m], BF[_ks][_n], acc[(qm)*4+_m][(qn)*2+_n], 0, 0, 0); \
    __builtin_amdgcn_s_setprio(0); \
} while (0)

#define PBAR  __builtin_amdgcn_s_barrier()
#define LGKM0 asm volatile("s_waitcnt lgkmcnt(0)" ::: "memory")
#define VMC4  asm volatile("s_waitcnt vmcnt(4)" ::: "memory")
#define VMC0  asm volatile("s_waitcnt vmcnt(0)" ::: "memory")

    // ---- prologue: tile0 all four halves + tile1.{A0,B0}
    STAGE_A(0, 0, 0); STAGE_A(0, 1, 0); STAGE_B(0, 0, 0); STAGE_B(0, 1, 0);
    STAGE_A(1, 0, 1); STAGE_B(1, 0, 1);
    VMC4; PBAR;

    const int KT2 = KT >> 1;
    for (int it = 0; it < KT2; ++it) {
        const int T0 = 2 * it, T1 = 2 * it + 1;
        const bool notlast = (it < KT2 - 1);
        // P1
        READ_A(0, 0); READ_B(0, 0, b0F);
        STAGE_A(1, 1, T1);
        PBAR; LGKM0; MFQ(0, 0, b0F); PBAR;
        // P2
        READ_B(0, 1, b1F);
        STAGE_B(1, 1, T1);
        PBAR; LGKM0; MFQ(0, 1, b1F); PBAR;
        // P3
        READ_A(0, 1);
        if (notlast) STAGE_B(0, 0, T0 + 2);
        PBAR; LGKM0; MFQ(1, 0, b0F); PBAR;
        // P4
        if (notlast) STAGE_A(0, 0, T0 + 2);
        PBAR; LGKM0; MFQ(1, 1, b1F);
        if (notlast) { VMC4; } else { VMC0; }
        PBAR;
        // P5
        READ_A(1, 0); READ_B(1, 0, b0F);
        if (notlast) STAGE_A(0, 1, T0 + 2);
        PBAR; LGKM0; MFQ(0, 0, b0F); PBAR;
        // P6
        READ_B(1, 1, b1F);
        if (notlast) STAGE_B(0, 1, T0 + 2);
        PBAR; LGKM0; MFQ(0, 1, b1F); PBAR;
        // P7
        READ_A(1, 1);
        if (notlast) STAGE_B(1, 0, T1 + 2);
        PBAR; LGKM0; MFQ(1, 0, b0F); PBAR;
        // P8
        if (notlast) STAGE_A(1, 0, T1 + 2);
        PBAR; LGKM0; MFQ(1, 1, b1F);
        if (notlast) { VMC4; } else { VMC0; }
        PBAR;
    }

#undef STAGE_A
#undef STAGE_B
#undef READ_A
#undef READ_B
#undef MFQ

    // ---- epilogue: wave (wr,wc) owns rows [wr*128,+128), cols [wc*64,+64)
#pragma unroll
    for (int m = 0; m < 8; ++m)
#pragma unroll
        for (int n = 0; n < 4; ++n)
#pragma unroll
            for (int r = 0; r < 4; ++r) {
                int row = M0 + wr * 128 + m * 16 + quad * 4 + r;
                int col = N0 + wc * 64 + n * 16 + lrow;
                float v = acc[m][n][r];
                if constexpr (MODE == 1) {
                    if (col < 4096) z_out[(LL)row * 4096 + col] = (__bf16)v;
                    else            x_out[(LL)row * 4096 + (col - 4096)] = (__bf16)v;
                } else {
                    outf[(LL)row * ldc + col] = v;
                }
            }
}

// ---------------- B/C/dt strip GEMM via split-bf16 MFMA ----------------------
__global__ __launch_bounds__(256) void bcdt_gemm_kernel(
    const __bf16* __restrict__ Ahi, const __bf16* __restrict__ Alo,
    const __bf16* __restrict__ Whi, const __bf16* __restrict__ Wlo,
    const float* __restrict__ dtbi,
    float* __restrict__ bcr, float* __restrict__ dt)
{
    __shared__ __align__(16) __bf16 sAh[128 * 64];
    __shared__ __align__(16) __bf16 sAl[128 * 64];
    __shared__ __align__(16) __bf16 sWh[64 * 64];
    __shared__ __align__(16) __bf16 sWl[64 * 64];
    const int orig = blockIdx.x;
    const int swz = (orig & 7) * 40 + (orig >> 3);
    const int m0 = (swz / 5) * 128;
    const int n0 = (swz % 5) * 64;
    const int tid = threadIdx.x;
    const int lane = tid & 63, wave = tid >> 6;
    const int lrow = lane & 15, quad = lane >> 4;
    const int wm = wave * 32;
    v4f acc[2][4] = {};

    for (int k0 = 0; k0 < 2048; k0 += 64) {
#pragma unroll
        for (int i = 0; i < 4; ++i) {
            int e = tid + i * 256;
            int row = e >> 3, g = (e & 7) ^ (row & 7);
            const LL so = (LL)(m0 + row) * 2048 + k0 + g * 8;
            gload_lds16(&Ahi[so], &sAh[wave * 512 + i * 2048]);
            gload_lds16(&Alo[so], &sAl[wave * 512 + i * 2048]);
        }
#pragma unroll
        for (int i = 0; i < 2; ++i) {
            int e = tid + i * 256;
            int row = e >> 3, g = (e & 7) ^ (row & 7);
            const LL so = (LL)(n0 + row) * 2048 + k0 + g * 8;
            gload_lds16(&Whi[so], &sWh[wave * 512 + i * 2048]);
            gload_lds16(&Wlo[so], &sWl[wave * 512 + i * 2048]);
        }
        __syncthreads();
#pragma unroll
        for (int ks = 0; ks < 2; ++ks) {
            v8bf ah[2], al[2], wh[4], wl[4];
#pragma unroll
            for (int i = 0; i < 2; ++i) {
                int r = wm + i * 16 + lrow;
                int c = ((((ks << 2) + quad) ^ (lrow & 7)) << 3);
                ah[i] = *(const v8bf*)&sAh[r * 64 + c];
                al[i] = *(const v8bf*)&sAl[r * 64 + c];
            }
#pragma unroll
            for (int j = 0; j < 4; ++j) {
                int r = j * 16 + lrow;
                int c = ((((ks << 2) + quad) ^ (lrow & 7)) << 3);
                wh[j] = *(const v8bf*)&sWh[r * 64 + c];
                wl[j] = *(const v8bf*)&sWl[r * 64 + c];
            }
#pragma unroll
            for (int i = 0; i < 2; ++i)
#pragma unroll
                for (int j = 0; j < 4; ++j) {
                    acc[i][j] = __builtin_amdgcn_mfma_f32_16x16x32_bf16(ah[i], wh[j], acc[i][j], 0, 0, 0);
                    acc[i][j] = __builtin_amdgcn_mfma_f32_16x16x32_bf16(ah[i], wl[j], acc[i][j], 0, 0, 0);
                    acc[i][j] = __builtin_amdgcn_mfma_f32_16x16x32_bf16(al[i], wh[j], acc[i][j], 0, 0, 0);
                }
        }
        __syncthreads();
    }
#pragma unroll
    for (int i = 0; i < 2; ++i)
#pragma unroll
        for (int j = 0; j < 4; ++j)
#pragma unroll
            for (int r = 0; r < 4; ++r) {
                int row = m0 + wm + i * 16 + quad * 4 + r;
                int sc = n0 + j * 16 + lrow;
                float v = acc[i][j][r];
                if (sc < 256) {
                    bcr[(LL)row * 256 + sc] = v;
                } else {
                    float x = v + dtbi[sc - 256];
                    dt[row * 64 + (sc - 256)] = (x > 20.f) ? x : log1pf(__expf(x));
                }
            }
}

// ---------------- causal conv1d (K=4) + SiLU, x channels (bf16) --------------
__global__ __launch_bounds__(256) void conv_x_kernel(
    const __bf16* __restrict__ xp, const float* __restrict__ cw,
    const float* __restrict__ cbias, __bf16* __restrict__ xq)
{
    int ch = blockIdx.x * 256 + threadIdx.x;
    int l = blockIdx.y, b = blockIdx.z;
    float acc = cbias[ch];
#pragma unroll
    for (int i = 0; i < 4; ++i) {
        int ls = l - 3 + i;
        if (ls >= 0)
            acc += (float)xp[((LL)b * 4096 + ls) * 4096 + ch] * cw[ch * 4 + i];
    }
    acc = acc / (1.f + __expf(-acc));
    xq[((LL)b * 4096 + l) * 4096 + ch] = (__bf16)acc;
}

// ---------------- causal conv1d (K=4) + SiLU, B/C channels (fp32) ------------
__global__ __launch_bounds__(256) void conv_bc_kernel(
    const float* __restrict__ bcr, const float* __restrict__ cw,
    const float* __restrict__ cbias, float* __restrict__ bcc)
{
    int ch = threadIdx.x;
    int l = blockIdx.y, b = blockIdx.z;
    float acc = cbias[4096 + ch];
#pragma unroll
    for (int i = 0; i < 4; ++i) {
        int ls = l - 3 + i;
        if (ls >= 0)
            acc += bcr[((LL)b * 4096 + ls) * 256 + ch] * cw[(4096 + ch) * 4 + i];
    }
    acc = acc / (1.f + __expf(-acc));
    bcc[((LL)b * 4096 + l) * 256 + ch] = acc;
}

// ---------------- per-chunk inclusive cumsum of dA = dt*A --------------------
__global__ __launch_bounds__(256) void cumsum_kernel(
    const float* __restrict__ dt, const float* __restrict__ alog,
    float* __restrict__ acs, float* __restrict__ cdec)
{
    int h = blockIdx.x, c = blockIdx.y, b = blockIdx.z;
    int s = threadIdx.x;
    __shared__ float buf[256];
    float Av = -expf(alog[h]);
    int bl = b * 4096 + c * 256 + s;
    buf[s] = dt[bl * 64 + h] * Av;
    __syncthreads();
    for (int off = 1; off < 256; off <<= 1) {
        float v = (s >= off) ? buf[s - off] : 0.f;
        __syncthreads();
        buf[s] += v;
        __syncthreads();
    }
    int abase = (((b * 16) + c) * 64 + h) * 256;
    acs[abase + s] = buf[s];
    if (s == 255) cdec[(b * 64 + h) * 16 + c] = expf(buf[s]);
}

// ---------------- chunk states: cs[b,c,h,p,n] = sum_s B[s,n]*dec[s]*x[s,p]*dt[s]
__global__ __launch_bounds__(256) void chunk_state_kernel(
    const __bf16* __restrict__ xq, const float* __restrict__ bcc,
    const float* __restrict__ dtb, const float* __restrict__ acs,
    float* __restrict__ cs)
{
    int h = blockIdx.x, c = blockIdx.y, b = blockIdx.z;
    int t = threadIdx.x;
    int lg = t & 63, pg = t >> 6;
    int n0 = lg * 2;
    __shared__ __align__(16) float xdt_s[64 * 68];
    __shared__ float dec_s[64];
    const LL lbase = (LL)b * 4096 + c * 256;
    const int abase = (((b * 16) + c) * 64 + h) * 256;
    float alast = acs[abase + 255];
    float a0[16] = {}, a1[16] = {};
    for (int st = 0; st < 4; ++st) {
        for (int i = 0; i < 16; ++i) {
            int e = t + i * 256; int sp = e >> 6, p = e & 63;
            LL row = lbase + st * 64 + sp;
            xdt_s[sp * 68 + p] = (float)xq[row * 4096 + h * 64 + p] * dtb[(row << 6) + h];
        }
        if (t < 64) dec_s[t] = __expf(alast - acs[abase + st * 64 + t]);
        __syncthreads();
        for (int sp = 0; sp < 64; ++sp) {
            LL row = lbase + st * 64 + sp;
            float2 bb = *(const float2*)&bcc[row * 256 + n0];
            float dd = dec_s[sp];
            float b0 = bb.x * dd, b1 = bb.y * dd;
#pragma unroll
            for (int q = 0; q < 4; ++q) {
                v4f xv = *(const v4f*)&xdt_s[sp * 68 + pg * 16 + q * 4];
#pragma unroll
                for (int j = 0; j < 4; ++j) { a0[q * 4 + j] += b0 * xv[j]; a1[q * 4 + j] += b1 * xv[j]; }
            }
        }
        __syncthreads();
    }
    const LL obase = ((LL)(((b * 16) + c) * 64 + h)) * 8192;
    for (int pp = 0; pp < 16; ++pp) {
        int p = pg * 16 + pp;
        cs[obase + p * 128 + n0]     = a0[pp];
        cs[obase + p * 128 + n0 + 1] = a1[pp];
    }
}

// ---------------- sequential scan over 16 chunks (IN PLACE: cs -> prev) ------
__global__ __launch_bounds__(256) void scan_kernel(
    float* __restrict__ cs, const float* __restrict__ cdec)
{
    int h = blockIdx.x, b = blockIdx.y;
    int t = threadIdx.x;
    float st[32];
#pragma unroll
    for (int i = 0; i < 32; ++i) st[i] = 0.f;
    for (int c = 0; c < 16; ++c) {
        LL base = ((LL)(((b * 16) + c) * 64 + h)) * 8192;
        float cd = cdec[(b * 64 + h) * 16 + c];
#pragma unroll
        for (int i = 0; i < 32; ++i) {
            int e = i * 256 + t;
            float v = cs[base + e];
            cs[base + e] = st[i];
            st[i] = st[i] * cd + v;
        }
    }
}

// ---------------- CBT[b,c,s,l] = sum_n B[s,n]*C[l,n]  ------------------------
// l-split: grid.x = 8 -> (st = x&3, lh = x>>2); each block: 64 s x 128 l.
__global__ __launch_bounds__(256) void cb_kernel(const float* __restrict__ bcc,
                                                 float* __restrict__ cbt)
{
    int bx = blockIdx.x;
    int st = bx & 3, lh = bx >> 2;
    int c = blockIdx.y, b = blockIdx.z;
    int t = threadIdx.x;
    int lg = t & 63, pg = t >> 6;
    __shared__ float cr_s[128 * 33];
    __shared__ __align__(16) float brT[32 * 68];
    const LL lbase = (LL)b * 4096 + c * 256;
    const int l0 = lh * 128;
    float acc[2][16] = {};
    for (int nt = 0; nt < 4; ++nt) {
        for (int i = 0; i < 16; ++i) {
            int e = t + i * 256; int l = e >> 5, np = e & 31;
            cr_s[l * 33 + np] = bcc[(lbase + l0 + l) * 256 + 128 + nt * 32 + np];
        }
        for (int i = 0; i < 8; ++i) {
            int e = t + i * 256; int sp = e >> 5, np = e & 31;
            brT[np * 68 + sp] = bcc[(lbase + st * 64 + sp) * 256 + nt * 32 + np];
        }
        __syncthreads();
        for (int np = 0; np < 32; ++np) {
            float w0 = cr_s[lg * 33 + np], w1 = cr_s[(lg + 64) * 33 + np];
#pragma unroll
            for (int q = 0; q < 4; ++q) {
                v4f bv = *(const v4f*)&brT[np * 68 + pg * 16 + q * 4];
#pragma unroll
                for (int j = 0; j < 4; ++j) {
                    acc[0][q * 4 + j] += w0 * bv[j];
                    acc[1][q * 4 + j] += w1 * bv[j];
                }
            }
        }
        __syncthreads();
    }
    const LL obase = ((LL)((b * 16) + c)) * 65536;
#pragma unroll
    for (int r = 0; r < 2; ++r)
        for (int sp = 0; sp < 16; ++sp) {
            int s = st * 64 + pg * 16 + sp;
            cbt[obase + (LL)s * 256 + (l0 + lg + r * 64)] = acc[r][sp];
        }
}

// ---------------- SSD output via MFMA: Y[256,64] = A[256,384]·Bm[384,64] -----
// R3 skeleton, factorized exp:
//   qbuf[kb][s'] = exp(acs[kb*64+63] - acs[kb*64+s']) precomputed once.
//   thread t (wave w = t>>6), phase kb<4:
//     kb <  w: A[t][s'] = cbt * (r * qbuf[kb][s']),  r = exp(acs[t]-m_kb)
//     kb == w: masked per-element exp (diagonal block)
//     kb >  w: rows structurally zero -> no loads/writes; wave skips MFMA.
__global__ __launch_bounds__(256) void ssd_y_kernel(
    __bf16* __restrict__ xq, const float* __restrict__ bcc,
    const float* __restrict__ dtb, const float* __restrict__ acs,
    const float* __restrict__ cbt, const float* __restrict__ prevS,
    const float* __restrict__ Dv)
{
    const int h = blockIdx.x, c = blockIdx.y, b = blockIdx.z;
    const int t = threadIdx.x;
    const int lane = t & 63, wave = t >> 6;
    const int lrow = lane & 15, quad = lane >> 4;
    const int wm = wave * 64;
    __shared__ __align__(16) __bf16 As[256][72];     // rows l, 64 k (+8 pad)
    __shared__ __align__(16) __bf16 Bs[64 * 64];     // swizzled [p][k]
    __shared__ float acs_s[256];
    __shared__ float qbuf[4][64];
    const LL lbase = (LL)b * 4096 + c * 256;
    const int abase = (((b * 16) + c) * 64 + h) * 256;
    acs_s[t] = acs[abase + t];
    __syncthreads();
    // qbuf: thread t covers block t>>6, elem t&63 (1 exp/thread, <=1 always)
    qbuf[t >> 6][t & 63] = __expf(acs_s[(t >> 6) * 64 + 63] - acs_s[t]);
    const float acl_t = acs_s[t];                    // builder row l = t
    const float ea_t  = __expf(acl_t);
    __syncthreads();
    const LL cbbase = ((LL)((b * 16) + c)) * 65536;
    const LL pbase  = ((LL)(((b * 16) + c) * 64 + h)) * 8192;
    v4f acc[4][4] = {};

    for (int kb = 0; kb < 6; ++kb) {
        // ---- build A tile (thread t owns row l = t)
        if (kb < 4) {
            const int sb = kb * 64;
            if (kb < wave) {
                // factorized off-diagonal: 1 exp + 64 mults
                const float r = __expf(acl_t - acs_s[sb + 63]);   // <= 1
#pragma unroll
                for (int g = 0; g < 8; ++g) {
                    v8bf wv;
#pragma unroll
                    for (int u = 0; u < 8; ++u) {
                        float cbv = cbt[cbbase + (LL)(sb + g * 8 + u) * 256 + t];
                        wv[u] = (__bf16)(cbv * (r * qbuf[kb][g * 8 + u]));
                    }
                    *(v8bf*)&As[t][g * 8] = wv;
                }
            } else if (kb == wave) {
                // diagonal block: masked per-element exp (overflow-safe)
#pragma unroll
                for (int g = 0; g < 8; ++g) {
                    v8bf wv;
#pragma unroll
                    for (int u = 0; u < 8; ++u) {
                        int s = sb + g * 8 + u;
                        float cbv = cbt[cbbase + (LL)s * 256 + t];
                        float d = acl_t - acs_s[s];
                        wv[u] = (__bf16)((s <= t) ? cbv * __expf(d) : 0.f);
                    }
                    *(v8bf*)&As[t][g * 8] = wv;
                }
            }
            // kb > wave: rows zero, never read (wave skips MFMA) — no work.
            // B tile: xdt, swizzled [p][s]
#pragma unroll
            for (int i = 0; i < 16; ++i) {
                int e = t + i * 256; int p = e & 63, sp = e >> 6;
                LL row = lbase + sb + sp;
                float xv = (float)xq[row * 4096 + h * 64 + p] * dtb[((int)row) * 64 + h];
                Bs[p * 64 + ((((sp >> 3) ^ (p & 7)) << 3) | (sp & 7))] = (__bf16)xv;
            }
        } else {
            const int nb = (kb - 4) * 64;
            const LL cb0 = (lbase + t) * 256 + 128 + nb;
#pragma unroll
            for (int g = 0; g < 8; ++g) {
                v4f c0 = *(const v4f*)&bcc[cb0 + g * 8];
                v4f c1 = *(const v4f*)&bcc[cb0 + g * 8 + 4];
                v8bf wv;
#pragma unroll
                for (int u = 0; u < 4; ++u) {
                    wv[u]     = (__bf16)(c0[u] * ea_t);
                    wv[u + 4] = (__bf16)(c1[u] * ea_t);
                }
                *(v8bf*)&As[t][g * 8] = wv;
            }
            // B tile: prev states
#pragma unroll
            for (int i = 0; i < 16; ++i) {
                int e = t + i * 256; int n = e & 63, p = e >> 6;
                float pv = prevS[pbase + (LL)p * 128 + nb + n];
                Bs[p * 64 + ((((n >> 3) ^ (p & 7)) << 3) | (n & 7))] = (__bf16)pv;
            }
        }
        __syncthreads();
        // ---- MFMA: 2 ksteps of 32 (waves above their diagonal skip: A zero)
        if (kb >= 4 || wave >= kb) {
#pragma unroll
            for (int ks = 0; ks < 2; ++ks) {
                v8bf af[4], bfv[4];
#pragma unroll
                for (int i = 0; i < 4; ++i)
                    af[i] = *(const v8bf*)&As[wm + i * 16 + lrow][ks * 32 + quad * 8];
#pragma unroll
                for (int j = 0; j < 4; ++j) {
                    int p = j * 16 + lrow;
                    int kg = (ks * 4 + quad) ^ (p & 7);
                    bfv[j] = *(const v8bf*)&Bs[p * 64 + kg * 8];
                }
#pragma unroll
                for (int i = 0; i < 4; ++i)
#pragma unroll
                    for (int j = 0; j < 4; ++j)
                        acc[i][j] = __builtin_amdgcn_mfma_f32_16x16x32_bf16(af[i], bfv[j], acc[i][j], 0, 0, 0);
            }
        }
        __syncthreads();
    }
    // ---- epilogue: + D*x, write Y over x region (owner lane reads own cell)
    const float Dh = Dv[h];
#pragma unroll
    for (int i = 0; i < 4; ++i)
#pragma unroll
        for (int j = 0; j < 4; ++j)
#pragma unroll
            for (int r = 0; r < 4; ++r) {
                int l = wm + i * 16 + quad * 4 + r;
                int p = j * 16 + lrow;
                LL idx = (lbase + l) * 4096 + h * 64 + p;
                float v = acc[i][j][r] + Dh * (float)xq[idx];
                xq[idx] = (__bf16)v;
            }
}

// ---------------- gated RMSNorm (in-place on xq, stride 4096) ----------------
__global__ __launch_bounds__(256) void rmsnorm_kernel(
    __bf16* __restrict__ y, const __bf16* __restrict__ z,
    const float* __restrict__ nw)
{
    LL r = blockIdx.x;
    int t = threadIdx.x;
    float vals[16]; float ss = 0.f;
#pragma unroll
    for (int i = 0; i < 16; ++i) {
        int j = i * 256 + t;
        float yv = (float)y[r * 4096 + j];
        float zv = (float)z[r * 4096 + j];
        float v = yv * (zv / (1.f + __expf(-zv)));
        vals[i] = v; ss += v * v;
    }
#pragma unroll
    for (int off = 32; off >= 1; off >>= 1) ss += __shfl_down(ss, off, 64);
    __shared__ float red[4];
    if ((t & 63) == 0) red[t >> 6] = ss;
    __syncthreads();
    float tot = red[0] + red[1] + red[2] + red[3];
    float rstd = rsqrtf(tot * (1.f / 4096.f) + 1e-5f);
#pragma unroll
    for (int i = 0; i < 16; ++i) {
        int j = i * 256 + t;
        y[r * 4096 + j] = (__bf16)(vals[i] * rstd * nw[j]);
    }
}

// ---------------------------------------------------------------------------
extern "C" void kernel_launch(void* const* d_in, const int* in_sizes, int n_in,
                              void* d_out, int out_size, void* d_ws, size_t ws_size,
                              hipStream_t stream) {
    const float* hs    = (const float*)d_in[0];
    const float* w1    = (const float*)d_in[1];
    const float* cw    = (const float*)d_in[2];
    const float* cbias = (const float*)d_in[3];
    const float* dtbi  = (const float*)d_in[4];
    const float* alog  = (const float*)d_in[5];
    const float* Dv    = (const float*)d_in[6];
    const float* nw    = (const float*)d_in[7];
    const float* wo    = (const float*)d_in[8];
    float* out = (float*)d_out;
    (void)in_sizes; (void)n_in; (void)out_size; (void)ws_size;

    char* ws = (char*)d_ws;
    size_t off = 0;
    auto alloc = [&](size_t bytes) { void* p = ws + off; off += (bytes + 255) & ~(size_t)255; return p; };
    __bf16* xp_b  = (__bf16*)alloc((size_t)8192 * 4096 * 2);
    __bf16* xq_b  = (__bf16*)alloc((size_t)8192 * 4096 * 2);
    float*  bcr_f = (float*) alloc((size_t)8192 * 256 * 4);
    float*  bcc_f = (float*) alloc((size_t)8192 * 256 * 4);
    float*  dt_f  = (float*) alloc((size_t)8192 * 64 * 4);
    float*  acs_f = (float*) alloc((size_t)2 * 16 * 64 * 256 * 4);
    float*  cd_f  = (float*) alloc((size_t)2 * 64 * 16 * 4);
    float*  cbt_f = (float*) alloc((size_t)2 * 16 * 256 * 256 * 4);
    float*  cs_f  = (float*)xp_b;           // aliases xp_b AFTER conv_x
    __bf16* z_b   = (__bf16*)d_out;

    __bf16* hs_b  = xq_b;                          // 8192*2048 bf16 = 32 MiB
    __bf16* w1_b  = xq_b + (size_t)8192 * 2048;    // 8192*2048 bf16 = 32 MiB
    __bf16* hs_lo = (__bf16*)xp_b;                 // 8192*2048 bf16 = 32 MiB
    __bf16* ws_hi = hs_lo + (size_t)8192 * 2048;   // 320*2048 bf16
    __bf16* ws_lo = ws_hi + (size_t)320 * 2048;    // 320*2048 bf16
    __bf16* wo_b  = (__bf16*)xp_b;                 // 2048*4096 bf16 = 16 MiB

    cast_split_kernel<<<8192, 256, 0, stream>>>(hs, hs_b, hs_lo);
    cast_bf16_kernel<<<8192, 256, 0, stream>>>(w1, w1_b);   // rows 0..8191
    cast_split_kernel<<<320, 256, 0, stream>>>(w1 + (size_t)8192 * 2048, ws_hi, ws_lo);
    // B/C/dt strip (reads xp_b aliases) BEFORE gemm1 overwrites xp_b
    bcdt_gemm_kernel<<<320, 256, 0, stream>>>(hs_b, hs_lo, ws_hi, ws_lo,
                                              dtbi, bcr_f, dt_f);
    // GEMM1: M=8192 N=8192 K=2048 -> 32x32 tiles, XCD regions 16x8
    gemm_bt_8p<1, 32, 32, 4><<<dim3(1024), 512, 0, stream>>>(
        hs_b, w1_b, 32, 2048, 2048, z_b, xp_b, nullptr, 0);
    conv_x_kernel<<<dim3(16, 4096, 2), 256, 0, stream>>>(xp_b, cw, cbias, xq_b);
    conv_bc_kernel<<<dim3(1, 4096, 2), 256, 0, stream>>>(bcr_f, cw, cbias, bcc_f);
    cumsum_kernel<<<dim3(64, 16, 2), 256, 0, stream>>>(dt_f, alog, acs_f, cd_f);
    chunk_state_kernel<<<dim3(64, 16, 2), 256, 0, stream>>>(xq_b, bcc_f, dt_f, acs_f, cs_f);
    scan_kernel<<<dim3(64, 2), 256, 0, stream>>>(cs_f, cd_f);
    cb_kernel<<<dim3(8, 16, 2), 256, 0, stream>>>(bcc_f, cbt_f);
    ssd_y_kernel<<<dim3(64, 16, 2), 256, 0, stream>>>(xq_b, bcc_f, dt_f, acs_f, cbt_f, cs_f, Dv);
    cast_bf16_kernel<<<4096, 256, 0, stream>>>(wo, wo_b);   // 2048*4096
    rmsnorm_kernel<<<8192, 256, 0, stream>>>(xq_b, z_b, nw);
    // GEMM2: M=8192 N=2048 K=4096 -> 32x8 tiles, XCD regions 4x8
    gemm_bt_8p<2, 32, 8, 1><<<dim3(256), 512, 0, stream>>>(
        xq_b, wo_b, 64, 4096, 4096, nullptr, nullptr, out, 2048);
}

// Round 6
// 1180.295 us; speedup vs baseline: 1.3925x; 1.2352x over previous
//
#include <hip/hip_runtime.h>
#include <hip/hip_bf16.h>

// ---------------------------------------------------------------------------
// Mamba2 mixer forward on MI355X (gfx950).
// HID=2048 DSTATE=128 K=4 DIN=4096 HDIM=64 NH=64 CHUNK=256, B=2 L=4096
//
// Precision plan (absmax budget 0.108, ref fp32):
//   - B, C, dt computed at ~fp32 precision via split-bf16 MFMA.
//   - ssd_y: W=CB*Lmat and C*exp(Acs) rounded to bf16 AFTER fp32 math, then
//     bf16 MFMA. x path bf16 throughout.
//
// R6 change (post-mortem R5: exp-reduction was null -> ssd_y is load-latency
// serialized, not VALU-bound; 85% all-pipes-idle at 23% occupancy):
//   - cbt stored TRANSPOSED (cbT[l][s]): ssd_y A-gather becomes 16 contiguous
//     dwordx4 loads/thread (was 64 scattered dwords). cb_kernel writes the
//     transpose via per-thread v4f stores (acc layout is already s-contig)
//     and skips the 2/8 above-diagonal output blocks (never read).
//   - ssd_y l-split: 128-thread blocks own 128 rows; grid 4096; LDS 26.3KB
//     (As XOR-swizzled, unpadded) -> ~6 blocks/CU. lh=0 blocks skip k-blocks
//     2,3 entirely (staging+barriers included).
//   - B-tile staging vectorized (ushort2 / float2).
// ---------------------------------------------------------------------------

typedef __bf16 v8bf __attribute__((ext_vector_type(8)));
typedef float  v4f  __attribute__((ext_vector_type(4)));

#define LL long long

__device__ inline v8bf load8(const float* p) {
    v4f a = *(const v4f*)p, b = *(const v4f*)(p + 4);
    v8bf r;
#pragma unroll
    for (int i = 0; i < 4; ++i) { r[i] = (__bf16)a[i]; r[i + 4] = (__bf16)b[i]; }
    return r;
}

__device__ __forceinline__ void gload_lds16(const __bf16* g, __bf16* l) {
    __builtin_amdgcn_global_load_lds(
        (const __attribute__((address_space(1))) void*)g,
        (__attribute__((address_space(3))) void*)l, 16, 0, 0);
}

// ---------------- fp32 -> bf16 cast (memory-bound, vectorized) ---------------
__global__ __launch_bounds__(256) void cast_bf16_kernel(
    const float* __restrict__ in, __bf16* __restrict__ out)
{
    LL i = ((LL)blockIdx.x * 256 + threadIdx.x) * 8;
    *(v8bf*)&out[i] = load8(&in[i]);
}

// ---------------- fp32 -> bf16 hi/lo split cast ------------------------------
__global__ __launch_bounds__(256) void cast_split_kernel(
    const float* __restrict__ in, __bf16* __restrict__ hi,
    __bf16* __restrict__ lo)
{
    LL i = ((LL)blockIdx.x * 256 + threadIdx.x) * 8;
    v4f a = *(const v4f*)&in[i], b = *(const v4f*)&in[i + 4];
    v8bf h, l;
#pragma unroll
    for (int k = 0; k < 4; ++k) {
        __bf16 hh = (__bf16)a[k];  h[k]     = hh;  l[k]     = (__bf16)(a[k] - (float)hh);
        __bf16 hb = (__bf16)b[k];  h[k + 4] = hb;  l[k + 4] = (__bf16)(b[k] - (float)hb);
    }
    *(v8bf*)&hi[i] = h;
    *(v8bf*)&lo[i] = l;
}

// ---------------- 256x256 8-phase bf16 GEMM:  C[M,N] = A[M,K]*B[N,K]^T ------
template <int MODE, int TM, int TN, int RN>
__global__ __launch_bounds__(512, 2) void gemm_bt_8p(
    const __bf16* __restrict__ Ab, const __bf16* __restrict__ Bb, int KT,
    int lda, int ldb,
    __bf16* __restrict__ z_out, __bf16* __restrict__ x_out,
    float* __restrict__ outf, int ldc)
{
    __shared__ __align__(16) __bf16 lds[65536];      // 128 KiB
    constexpr int RM = 8 / RN;
    constexpr int LM = TM / RM, LN = TN / RN;
    const int orig = blockIdx.x;
    const int x = orig & 7, loc = orig >> 3;
    const int M0 = ((x / RN) * LM + loc / LN) * 256;
    const int N0 = ((x % RN) * LN + loc % LN) * 256;

    const int tid  = threadIdx.x;
    const int lane = tid & 63, wave = tid >> 6;
    const int wr = wave >> 2, wc = wave & 3;         // 2x4 wave grid
    const int lrow = lane & 15, quad = lane >> 4;
    const int row0 = tid >> 3;                       // staging row 0..63
    const int g0   = (tid & 7) ^ (row0 & 7);         // inverse-swizzled chunk

    v4f acc[8][4] = {};
    v8bf aF[2][4], b0F[2][2], b1F[2][2];

#define STAGE_A(par, half, kt) do { \
    const __bf16* _s = Ab + (size_t)(M0 + (half)*128 + row0) * lda + (kt)*64 + g0*8; \
    __bf16* _d = lds + ((par)*2 + (half)) * 8192 + wave * 512; \
    gload_lds16(_s, _d); \
    gload_lds16(_s + (size_t)64 * lda, _d + 4096); \
} while (0)

#define STAGE_B(par, half, kt) do { \
    const __bf16* _s = Bb + (size_t)(N0 + (half)*128 + row0) * ldb + (kt)*64 + g0*8; \
    __bf16* _d = lds + 32768 + ((par)*2 + (half)) * 8192 + wave * 512; \
    gload_lds16(_s, _d); \
    gload_lds16(_s + (size_t)64 * ldb, _d + 4096); \
} while (0)

#define READ_A(par, qm) do { \
    const __bf16* _s = lds + ((par)*2 + wr) * 8192; \
    _Pragma("unroll") \
    for (int _ks = 0; _ks < 2; ++_ks) \
      _Pragma("unroll") \
      for (int _m = 0; _m < 4; ++_m) \
        aF[_ks][_m] = *(const v8bf*)&_s[((qm)*64 + _m*16 + lrow)*64 + \
                                        ((((_ks<<2)+quad) ^ (lrow&7))<<3)]; \
} while (0)

#define READ_B(par, qn, DST) do { \
    const __bf16* _s = lds + 32768 + ((par)*2 + (wc>>1)) * 8192; \
    _Pragma("unroll") \
    for (int _ks = 0; _ks < 2; ++_ks) \
      _Pragma("unroll") \
      for (int _n = 0; _n < 2; ++_n) \
        DST[_ks][_n] = *(const v8bf*)&_s[((wc&1)*64 + (qn)*32 + _n*16 + lrow)*64 + \
                                         ((((_ks<<2)+quad) ^ (lrow&7))<<3)]; \
} while (0)

#define MFQ(qm, qn, BF) do { \
    __builtin_amdgcn_s_setprio(1); \
    _Pragma("unroll") \
    for (int _ks = 0; _ks < 2; ++_ks) \
      _Pragma("unroll") \
      for (int _m = 0; _m < 4; ++_m) \
        _Pragma("unroll") \
        for (int _n = 0; _n < 2; ++_n) \
          acc[(qm)*4+_m][(qn)*2+_n] = __builtin_amdgcn_mfma_f32_16x16x32_bf16( \
              aF[_ks][_m], BF[_ks][_n], acc[(qm)*4+_m][(qn)*2+_n], 0, 0, 0); \
    __builtin_amdgcn_s_setprio(0); \
} while (0)

#define PBAR  __builtin_amdgcn_s_barrier()
#define LGKM0 asm volatile("s_waitcnt lgkmcnt(0)" ::: "memory")
#define VMC4  asm volatile("s_waitcnt vmcnt(4)" ::: "memory")
#define VMC0  asm volatile("s_waitcnt vmcnt(0)" ::: "memory")

    // ---- prologue: tile0 all four halves + tile1.{A0,B0}
    STAGE_A(0, 0, 0); STAGE_A(0, 1, 0); STAGE_B(0, 0, 0); STAGE_B(0, 1, 0);
    STAGE_A(1, 0, 1); STAGE_B(1, 0, 1);
    VMC4; PBAR;

    const int KT2 = KT >> 1;
    for (int it = 0; it < KT2; ++it) {
        const int T0 = 2 * it, T1 = 2 * it + 1;
        const bool notlast = (it < KT2 - 1);
        // P1
        READ_A(0, 0); READ_B(0, 0, b0F);
        STAGE_A(1, 1, T1);
        PBAR; LGKM0; MFQ(0, 0, b0F); PBAR;
        // P2
        READ_B(0, 1, b1F);
        STAGE_B(1, 1, T1);
        PBAR; LGKM0; MFQ(0, 1, b1F); PBAR;
        // P3
        READ_A(0, 1);
        if (notlast) STAGE_B(0, 0, T0 + 2);
        PBAR; LGKM0; MFQ(1, 0, b0F); PBAR;
        // P4
        if (notlast) STAGE_A(0, 0, T0 + 2);
        PBAR; LGKM0; MFQ(1, 1, b1F);
        if (notlast) { VMC4; } else { VMC0; }
        PBAR;
        // P5
        READ_A(1, 0); READ_B(1, 0, b0F);
        if (notlast) STAGE_A(0, 1, T0 + 2);
        PBAR; LGKM0; MFQ(0, 0, b0F); PBAR;
        // P6
        READ_B(1, 1, b1F);
        if (notlast) STAGE_B(0, 1, T0 + 2);
        PBAR; LGKM0; MFQ(0, 1, b1F); PBAR;
        // P7
        READ_A(1, 1);
        if (notlast) STAGE_B(1, 0, T1 + 2);
        PBAR; LGKM0; MFQ(1, 0, b0F); PBAR;
        // P8
        if (notlast) STAGE_A(1, 0, T1 + 2);
        PBAR; LGKM0; MFQ(1, 1, b1F);
        if (notlast) { VMC4; } else { VMC0; }
        PBAR;
    }

#undef STAGE_A
#undef STAGE_B
#undef READ_A
#undef READ_B
#undef MFQ

    // ---- epilogue: wave (wr,wc) owns rows [wr*128,+128), cols [wc*64,+64)
#pragma unroll
    for (int m = 0; m < 8; ++m)
#pragma unroll
        for (int n = 0; n < 4; ++n)
#pragma unroll
            for (int r = 0; r < 4; ++r) {
                int row = M0 + wr * 128 + m * 16 + quad * 4 + r;
                int col = N0 + wc * 64 + n * 16 + lrow;
                float v = acc[m][n][r];
                if constexpr (MODE == 1) {
                    if (col < 4096) z_out[(LL)row * 4096 + col] = (__bf16)v;
                    else            x_out[(LL)row * 4096 + (col - 4096)] = (__bf16)v;
                } else {
                    outf[(LL)row * ldc + col] = v;
                }
            }
}

// ---------------- B/C/dt strip GEMM via split-bf16 MFMA ----------------------
__global__ __launch_bounds__(256) void bcdt_gemm_kernel(
    const __bf16* __restrict__ Ahi, const __bf16* __restrict__ Alo,
    const __bf16* __restrict__ Whi, const __bf16* __restrict__ Wlo,
    const float* __restrict__ dtbi,
    float* __restrict__ bcr, float* __restrict__ dt)
{
    __shared__ __align__(16) __bf16 sAh[128 * 64];
    __shared__ __align__(16) __bf16 sAl[128 * 64];
    __shared__ __align__(16) __bf16 sWh[64 * 64];
    __shared__ __align__(16) __bf16 sWl[64 * 64];
    const int orig = blockIdx.x;
    const int swz = (orig & 7) * 40 + (orig >> 3);
    const int m0 = (swz / 5) * 128;
    const int n0 = (swz % 5) * 64;
    const int tid = threadIdx.x;
    const int lane = tid & 63, wave = tid >> 6;
    const int lrow = lane & 15, quad = lane >> 4;
    const int wm = wave * 32;
    v4f acc[2][4] = {};

    for (int k0 = 0; k0 < 2048; k0 += 64) {
#pragma unroll
        for (int i = 0; i < 4; ++i) {
            int e = tid + i * 256;
            int row = e >> 3, g = (e & 7) ^ (row & 7);
            const LL so = (LL)(m0 + row) * 2048 + k0 + g * 8;
            gload_lds16(&Ahi[so], &sAh[wave * 512 + i * 2048]);
            gload_lds16(&Alo[so], &sAl[wave * 512 + i * 2048]);
        }
#pragma unroll
        for (int i = 0; i < 2; ++i) {
            int e = tid + i * 256;
            int row = e >> 3, g = (e & 7) ^ (row & 7);
            const LL so = (LL)(n0 + row) * 2048 + k0 + g * 8;
            gload_lds16(&Whi[so], &sWh[wave * 512 + i * 2048]);
            gload_lds16(&Wlo[so], &sWl[wave * 512 + i * 2048]);
        }
        __syncthreads();
#pragma unroll
        for (int ks = 0; ks < 2; ++ks) {
            v8bf ah[2], al[2], wh[4], wl[4];
#pragma unroll
            for (int i = 0; i < 2; ++i) {
                int r = wm + i * 16 + lrow;
                int c = ((((ks << 2) + quad) ^ (lrow & 7)) << 3);
                ah[i] = *(const v8bf*)&sAh[r * 64 + c];
                al[i] = *(const v8bf*)&sAl[r * 64 + c];
            }
#pragma unroll
            for (int j = 0; j < 4; ++j) {
                int r = j * 16 + lrow;
                int c = ((((ks << 2) + quad) ^ (lrow & 7)) << 3);
                wh[j] = *(const v8bf*)&sWh[r * 64 + c];
                wl[j] = *(const v8bf*)&sWl[r * 64 + c];
            }
#pragma unroll
            for (int i = 0; i < 2; ++i)
#pragma unroll
                for (int j = 0; j < 4; ++j) {
                    acc[i][j] = __builtin_amdgcn_mfma_f32_16x16x32_bf16(ah[i], wh[j], acc[i][j], 0, 0, 0);
                    acc[i][j] = __builtin_amdgcn_mfma_f32_16x16x32_bf16(ah[i], wl[j], acc[i][j], 0, 0, 0);
                    acc[i][j] = __builtin_amdgcn_mfma_f32_16x16x32_bf16(al[i], wh[j], acc[i][j], 0, 0, 0);
                }
        }
        __syncthreads();
    }
#pragma unroll
    for (int i = 0; i < 2; ++i)
#pragma unroll
        for (int j = 0; j < 4; ++j)
#pragma unroll
            for (int r = 0; r < 4; ++r) {
                int row = m0 + wm + i * 16 + quad * 4 + r;
                int sc = n0 + j * 16 + lrow;
                float v = acc[i][j][r];
                if (sc < 256) {
                    bcr[(LL)row * 256 + sc] = v;
                } else {
                    float x = v + dtbi[sc - 256];
                    dt[row * 64 + (sc - 256)] = (x > 20.f) ? x : log1pf(__expf(x));
                }
            }
}

// ---------------- causal conv1d (K=4) + SiLU, x channels (bf16) --------------
__global__ __launch_bounds__(256) void conv_x_kernel(
    const __bf16* __restrict__ xp, const float* __restrict__ cw,
    const float* __restrict__ cbias, __bf16* __restrict__ xq)
{
    int ch = blockIdx.x * 256 + threadIdx.x;
    int l = blockIdx.y, b = blockIdx.z;
    float acc = cbias[ch];
#pragma unroll
    for (int i = 0; i < 4; ++i) {
        int ls = l - 3 + i;
        if (ls >= 0)
            acc += (float)xp[((LL)b * 4096 + ls) * 4096 + ch] * cw[ch * 4 + i];
    }
    acc = acc / (1.f + __expf(-acc));
    xq[((LL)b * 4096 + l) * 4096 + ch] = (__bf16)acc;
}

// ---------------- causal conv1d (K=4) + SiLU, B/C channels (fp32) ------------
__global__ __launch_bounds__(256) void conv_bc_kernel(
    const float* __restrict__ bcr, const float* __restrict__ cw,
    const float* __restrict__ cbias, float* __restrict__ bcc)
{
    int ch = threadIdx.x;
    int l = blockIdx.y, b = blockIdx.z;
    float acc = cbias[4096 + ch];
#pragma unroll
    for (int i = 0; i < 4; ++i) {
        int ls = l - 3 + i;
        if (ls >= 0)
            acc += bcr[((LL)b * 4096 + ls) * 256 + ch] * cw[(4096 + ch) * 4 + i];
    }
    acc = acc / (1.f + __expf(-acc));
    bcc[((LL)b * 4096 + l) * 256 + ch] = acc;
}

// ---------------- per-chunk inclusive cumsum of dA = dt*A --------------------
__global__ __launch_bounds__(256) void cumsum_kernel(
    const float* __restrict__ dt, const float* __restrict__ alog,
    float* __restrict__ acs, float* __restrict__ cdec)
{
    int h = blockIdx.x, c = blockIdx.y, b = blockIdx.z;
    int s = threadIdx.x;
    __shared__ float buf[256];
    float Av = -expf(alog[h]);
    int bl = b * 4096 + c * 256 + s;
    buf[s] = dt[bl * 64 + h] * Av;
    __syncthreads();
    for (int off = 1; off < 256; off <<= 1) {
        float v = (s >= off) ? buf[s - off] : 0.f;
        __syncthreads();
        buf[s] += v;
        __syncthreads();
    }
    int abase = (((b * 16) + c) * 64 + h) * 256;
    acs[abase + s] = buf[s];
    if (s == 255) cdec[(b * 64 + h) * 16 + c] = expf(buf[s]);
}

// ---------------- chunk states: cs[b,c,h,p,n] = sum_s B[s,n]*dec[s]*x[s,p]*dt[s]
__global__ __launch_bounds__(256) void chunk_state_kernel(
    const __bf16* __restrict__ xq, const float* __restrict__ bcc,
    const float* __restrict__ dtb, const float* __restrict__ acs,
    float* __restrict__ cs)
{
    int h = blockIdx.x, c = blockIdx.y, b = blockIdx.z;
    int t = threadIdx.x;
    int lg = t & 63, pg = t >> 6;
    int n0 = lg * 2;
    __shared__ __align__(16) float xdt_s[64 * 68];
    __shared__ float dec_s[64];
    const LL lbase = (LL)b * 4096 + c * 256;
    const int abase = (((b * 16) + c) * 64 + h) * 256;
    float alast = acs[abase + 255];
    float a0[16] = {}, a1[16] = {};
    for (int st = 0; st < 4; ++st) {
        for (int i = 0; i < 16; ++i) {
            int e = t + i * 256; int sp = e >> 6, p = e & 63;
            LL row = lbase + st * 64 + sp;
            xdt_s[sp * 68 + p] = (float)xq[row * 4096 + h * 64 + p] * dtb[(row << 6) + h];
        }
        if (t < 64) dec_s[t] = __expf(alast - acs[abase + st * 64 + t]);
        __syncthreads();
        for (int sp = 0; sp < 64; ++sp) {
            LL row = lbase + st * 64 + sp;
            float2 bb = *(const float2*)&bcc[row * 256 + n0];
            float dd = dec_s[sp];
            float b0 = bb.x * dd, b1 = bb.y * dd;
#pragma unroll
            for (int q = 0; q < 4; ++q) {
                v4f xv = *(const v4f*)&xdt_s[sp * 68 + pg * 16 + q * 4];
#pragma unroll
                for (int j = 0; j < 4; ++j) { a0[q * 4 + j] += b0 * xv[j]; a1[q * 4 + j] += b1 * xv[j]; }
            }
        }
        __syncthreads();
    }
    const LL obase = ((LL)(((b * 16) + c) * 64 + h)) * 8192;
    for (int pp = 0; pp < 16; ++pp) {
        int p = pg * 16 + pp;
        cs[obase + p * 128 + n0]     = a0[pp];
        cs[obase + p * 128 + n0 + 1] = a1[pp];
    }
}

// ---------------- sequential scan over 16 chunks (IN PLACE: cs -> prev) ------
__global__ __launch_bounds__(256) void scan_kernel(
    float* __restrict__ cs, const float* __restrict__ cdec)
{
    int h = blockIdx.x, b = blockIdx.y;
    int t = threadIdx.x;
    float st[32];
#pragma unroll
    for (int i = 0; i < 32; ++i) st[i] = 0.f;
    for (int c = 0; c < 16; ++c) {
        LL base = ((LL)(((b * 16) + c) * 64 + h)) * 8192;
        float cd = cdec[(b * 64 + h) * 16 + c];
#pragma unroll
        for (int i = 0; i < 32; ++i) {
            int e = i * 256 + t;
            float v = cs[base + e];
            cs[base + e] = st[i];
            st[i] = st[i] * cd + v;
        }
    }
}

// ---------------- CBT^T[b,c,l,s] = sum_n B[s,n]*C[l,n]  ----------------------
// TRANSPOSED output (cbT[l*256+s]); only s<=l blocks (6 live (lh,st) combos).
// acc layout is s-contiguous per thread -> transposed write = 8 v4f stores.
__global__ __launch_bounds__(256) void cb_kernel(const float* __restrict__ bcc,
                                                 float* __restrict__ cbt)
{
    int bx = blockIdx.x;                      // 0..5
    int lh = (bx < 2) ? 0 : 1;
    int st = (bx < 2) ? bx : bx - 2;
    int c = blockIdx.y, b = blockIdx.z;
    int t = threadIdx.x;
    int lg = t & 63, pg = t >> 6;
    __shared__ float cr_s[128 * 33];
    __shared__ __align__(16) float brT[32 * 68];
    const LL lbase = (LL)b * 4096 + c * 256;
    const int l0 = lh * 128;
    v4f acc[2][4] = {};
    for (int nt = 0; nt < 4; ++nt) {
        for (int i = 0; i < 16; ++i) {
            int e = t + i * 256; int l = e >> 5, np = e & 31;
            cr_s[l * 33 + np] = bcc[(lbase + l0 + l) * 256 + 128 + nt * 32 + np];
        }
        for (int i = 0; i < 8; ++i) {
            int e = t + i * 256; int sp = e >> 5, np = e & 31;
            brT[np * 68 + sp] = bcc[(lbase + st * 64 + sp) * 256 + nt * 32 + np];
        }
        __syncthreads();
        for (int np = 0; np < 32; ++np) {
            float w0 = cr_s[lg * 33 + np], w1 = cr_s[(lg + 64) * 33 + np];
#pragma unroll
            for (int q = 0; q < 4; ++q) {
                v4f bv = *(const v4f*)&brT[np * 68 + pg * 16 + q * 4];
                acc[0][q] += w0 * bv;
                acc[1][q] += w1 * bv;
            }
        }
        __syncthreads();
    }
    const LL obase = ((LL)((b * 16) + c)) * 65536;
#pragma unroll
    for (int r = 0; r < 2; ++r) {
        LL rowb = obase + (LL)(l0 + lg + r * 64) * 256 + st * 64 + pg * 16;
#pragma unroll
        for (int q = 0; q < 4; ++q)
            *(v4f*)&cbt[rowb + q * 4] = acc[r][q];
    }
}

// ---------------- SSD output via MFMA (l-split, 128-thread blocks) -----------
// Block = (h, c, lh, b): rows [lh*128, +128). Thread t owns row l = lh*128+t.
// Wave w -> row-block rb = lh*2+w. Phase kb<4: kb<rb factorized (r*q), kb==rb
// masked diag exp, kb>rb skip build+MFMA. lh=0 blocks skip kb=2,3 entirely.
// A-gather from TRANSPOSED cbT[l][s]: 16 contiguous v4f loads per thread.
// As LDS: [128][64] bf16 XOR-swizzled (chunk g stored at g^(row&7)).
__global__ __launch_bounds__(128) void ssd_y_kernel(
    __bf16* __restrict__ xq, const float* __restrict__ bcc,
    const float* __restrict__ dtb, const float* __restrict__ acs,
    const float* __restrict__ cbtT, const float* __restrict__ prevS,
    const float* __restrict__ Dv)
{
    const int h = blockIdx.x;
    const int c = blockIdx.y >> 1, lh = blockIdx.y & 1;
    const int b = blockIdx.z;
    const int t = threadIdx.x;                // 0..127
    const int lane = t & 63, wave = t >> 6;
    const int lrow = lane & 15, quad = lane >> 4;
    const int rb = lh * 2 + wave;             // global row-block 0..3
    const int l = lh * 128 + t;               // global row owned by thread
    __shared__ __align__(16) __bf16 As[128 * 64];   // swizzled
    __shared__ __align__(16) __bf16 Bs[64 * 64];    // swizzled [p][k]
    __shared__ float acs_s[256];
    __shared__ float qbuf[4][64];
    const LL lbase = (LL)b * 4096 + c * 256;
    const int abase = (((b * 16) + c) * 64 + h) * 256;
    acs_s[t] = acs[abase + t];
    acs_s[t + 128] = acs[abase + t + 128];
    __syncthreads();
    qbuf[t >> 6][t & 63]       = __expf(acs_s[(t >> 6) * 64 + 63] - acs_s[t]);
    qbuf[2 + (t >> 6)][t & 63] = __expf(acs_s[(2 + (t >> 6)) * 64 + 63] - acs_s[128 + t]);
    const float acl_t = acs_s[l];
    const float ea_t  = __expf(acl_t);
    __syncthreads();
    const LL cbbase = ((LL)((b * 16) + c)) * 65536;
    const LL pbase  = ((LL)(((b * 16) + c) * 64 + h)) * 8192;
    const int rbmax = lh * 2 + 1;
    v4f acc[4][4] = {};

    for (int kb = 0; kb < 6; ++kb) {
        if (kb < 4 && kb > rbmax) continue;   // block-uniform skip (lh=0: kb 2,3)
        if (kb < 4) {
            const int sb = kb * 64;
            if (kb <= rb) {
                const LL crow = cbbase + (LL)l * 256 + sb;
                if (kb < rb) {
                    const float rf = __expf(acl_t - acs_s[sb + 63]);  // <= 1
#pragma unroll
                    for (int g = 0; g < 8; ++g) {
                        v4f c0 = *(const v4f*)&cbtT[crow + g * 8];
                        v4f c1 = *(const v4f*)&cbtT[crow + g * 8 + 4];
                        v8bf wv;
#pragma unroll
                        for (int u = 0; u < 4; ++u) {
                            wv[u]     = (__bf16)(c0[u] * (rf * qbuf[kb][g * 8 + u]));
                            wv[u + 4] = (__bf16)(c1[u] * (rf * qbuf[kb][g * 8 + 4 + u]));
                        }
                        *(v8bf*)&As[t * 64 + ((g ^ (t & 7)) << 3)] = wv;
                    }
                } else {  // diagonal block: masked per-element exp
#pragma unroll
                    for (int g = 0; g < 8; ++g) {
                        v4f c0 = *(const v4f*)&cbtT[crow + g * 8];
                        v4f c1 = *(const v4f*)&cbtT[crow + g * 8 + 4];
                        v8bf wv;
#pragma unroll
                        for (int u = 0; u < 4; ++u) {
                            int s0 = sb + g * 8 + u, s1 = s0 + 4;
                            wv[u]     = (__bf16)((s0 <= l) ? c0[u] * __expf(acl_t - acs_s[s0]) : 0.f);
                            wv[u + 4] = (__bf16)((s1 <= l) ? c1[u] * __expf(acl_t - acs_s[s1]) : 0.f);
                        }
                        *(v8bf*)&As[t * 64 + ((g ^ (t & 7)) << 3)] = wv;
                    }
                }
            }
            // B tile: xdt, swizzled [p][s] — ushort2-vectorized staging
#pragma unroll
            for (int i = 0; i < 16; ++i) {
                int e = t + i * 128; int pp = e & 31, sp = e >> 5;
                int p = pp * 2;
                LL row = lbase + sb + sp;
                float dv = dtb[((int)row) * 64 + h];
                ushort2 xu = *(const ushort2*)&xq[row * 4096 + h * 64 + p];
                __bf16 x0, x1;
                *(unsigned short*)&x0 = xu.x; *(unsigned short*)&x1 = xu.y;
                Bs[p * 64 + ((((sp >> 3) ^ (p & 7)) << 3) | (sp & 7))] = (__bf16)((float)x0 * dv);
                Bs[(p + 1) * 64 + ((((sp >> 3) ^ ((p + 1) & 7)) << 3) | (sp & 7))] = (__bf16)((float)x1 * dv);
            }
        } else {
            const int nb = (kb - 4) * 64;
            const LL cb0 = (lbase + l) * 256 + 128 + nb;
#pragma unroll
            for (int g = 0; g < 8; ++g) {
                v4f c0 = *(const v4f*)&bcc[cb0 + g * 8];
                v4f c1 = *(const v4f*)&bcc[cb0 + g * 8 + 4];
                v8bf wv;
#pragma unroll
                for (int u = 0; u < 4; ++u) {
                    wv[u]     = (__bf16)(c0[u] * ea_t);
                    wv[u + 4] = (__bf16)(c1[u] * ea_t);
                }
                *(v8bf*)&As[t * 64 + ((g ^ (t & 7)) << 3)] = wv;
            }
            // B tile: prev states — float2-vectorized staging
#pragma unroll
            for (int i = 0; i < 16; ++i) {
                int e = t + i * 128; int nn = e & 31, p = e >> 5;
                int n = nn * 2;
                float2 pv = *(const float2*)&prevS[pbase + (LL)p * 128 + nb + n];
                int chunk = ((n >> 3) ^ (p & 7));
                __bf16 b0 = (__bf16)pv.x, b1 = (__bf16)pv.y;
                __bf16* dst = &Bs[p * 64 + (chunk << 3) + (n & 7)];
                dst[0] = b0; dst[1] = b1;
            }
        }
        __syncthreads();
        // ---- MFMA: 2 ksteps of 32
        if (kb >= 4 || kb <= rb) {
#pragma unroll
            for (int ks = 0; ks < 2; ++ks) {
                v8bf af[4], bfv[4];
#pragma unroll
                for (int i = 0; i < 4; ++i) {
                    int row = wave * 64 + i * 16 + lrow;
                    af[i] = *(const v8bf*)&As[row * 64 + ((((ks << 2) + quad) ^ (lrow & 7)) << 3)];
                }
#pragma unroll
                for (int j = 0; j < 4; ++j) {
                    int p = j * 16 + lrow;
                    int kg = (ks * 4 + quad) ^ (p & 7);
                    bfv[j] = *(const v8bf*)&Bs[p * 64 + kg * 8];
                }
#pragma unroll
                for (int i = 0; i < 4; ++i)
#pragma unroll
                    for (int j = 0; j < 4; ++j)
                        acc[i][j] = __builtin_amdgcn_mfma_f32_16x16x32_bf16(af[i], bfv[j], acc[i][j], 0, 0, 0);
            }
        }
        __syncthreads();
    }
    // ---- epilogue: + D*x, write Y over x region (owner lane reads own cell)
    const float Dh = Dv[h];
#pragma unroll
    for (int i = 0; i < 4; ++i)
#pragma unroll
        for (int j = 0; j < 4; ++j)
#pragma unroll
            for (int r = 0; r < 4; ++r) {
                int ll = lh * 128 + wave * 64 + i * 16 + quad * 4 + r;
                int p = j * 16 + lrow;
                LL idx = (lbase + ll) * 4096 + h * 64 + p;
                float v = acc[i][j][r] + Dh * (float)xq[idx];
                xq[idx] = (__bf16)v;
            }
}

// ---------------- gated RMSNorm (in-place on xq, stride 4096) ----------------
__global__ __launch_bounds__(256) void rmsnorm_kernel(
    __bf16* __restrict__ y, const __bf16* __restrict__ z,
    const float* __restrict__ nw)
{
    LL r = blockIdx.x;
    int t = threadIdx.x;
    float vals[16]; float ss = 0.f;
#pragma unroll
    for (int i = 0; i < 16; ++i) {
        int j = i * 256 + t;
        float yv = (float)y[r * 4096 + j];
        float zv = (float)z[r * 4096 + j];
        float v = yv * (zv / (1.f + __expf(-zv)));
        vals[i] = v; ss += v * v;
    }
#pragma unroll
    for (int off = 32; off >= 1; off >>= 1) ss += __shfl_down(ss, off, 64);
    __shared__ float red[4];
    if ((t & 63) == 0) red[t >> 6] = ss;
    __syncthreads();
    float tot = red[0] + red[1] + red[2] + red[3];
    float rstd = rsqrtf(tot * (1.f / 4096.f) + 1e-5f);
#pragma unroll
    for (int i = 0; i < 16; ++i) {
        int j = i * 256 + t;
        y[r * 4096 + j] = (__bf16)(vals[i] * rstd * nw[j]);
    }
}

// ---------------------------------------------------------------------------
extern "C" void kernel_launch(void* const* d_in, const int* in_sizes, int n_in,
                              void* d_out, int out_size, void* d_ws, size_t ws_size,
                              hipStream_t stream) {
    const float* hs    = (const float*)d_in[0];
    const float* w1    = (const float*)d_in[1];
    const float* cw    = (const float*)d_in[2];
    const float* cbias = (const float*)d_in[3];
    const float* dtbi  = (const float*)d_in[4];
    const float* alog  = (const float*)d_in[5];
    const float* Dv    = (const float*)d_in[6];
    const float* nw    = (const float*)d_in[7];
    const float* wo    = (const float*)d_in[8];
    float* out = (float*)d_out;
    (void)in_sizes; (void)n_in; (void)out_size; (void)ws_size;

    char* ws = (char*)d_ws;
    size_t off = 0;
    auto alloc = [&](size_t bytes) { void* p = ws + off; off += (bytes + 255) & ~(size_t)255; return p; };
    __bf16* xp_b  = (__bf16*)alloc((size_t)8192 * 4096 * 2);
    __bf16* xq_b  = (__bf16*)alloc((size_t)8192 * 4096 * 2);
    float*  bcr_f = (float*) alloc((size_t)8192 * 256 * 4);
    float*  bcc_f = (float*) alloc((size_t)8192 * 256 * 4);
    float*  dt_f  = (float*) alloc((size_t)8192 * 64 * 4);
    float*  acs_f = (float*) alloc((size_t)2 * 16 * 64 * 256 * 4);
    float*  cd_f  = (float*) alloc((size_t)2 * 64 * 16 * 4);
    float*  cbt_f = (float*) alloc((size_t)2 * 16 * 256 * 256 * 4);
    float*  cs_f  = (float*)xp_b;           // aliases xp_b AFTER conv_x
    __bf16* z_b   = (__bf16*)d_out;

    __bf16* hs_b  = xq_b;                          // 8192*2048 bf16 = 32 MiB
    __bf16* w1_b  = xq_b + (size_t)8192 * 2048;    // 8192*2048 bf16 = 32 MiB
    __bf16* hs_lo = (__bf16*)xp_b;                 // 8192*2048 bf16 = 32 MiB
    __bf16* ws_hi = hs_lo + (size_t)8192 * 2048;   // 320*2048 bf16
    __bf16* ws_lo = ws_hi + (size_t)320 * 2048;    // 320*2048 bf16
    __bf16* wo_b  = (__bf16*)xp_b;                 // 2048*4096 bf16 = 16 MiB

    cast_split_kernel<<<8192, 256, 0, stream>>>(hs, hs_b, hs_lo);
    cast_bf16_kernel<<<8192, 256, 0, stream>>>(w1, w1_b);   // rows 0..8191
    cast_split_kernel<<<320, 256, 0, stream>>>(w1 + (size_t)8192 * 2048, ws_hi, ws_lo);
    // B/C/dt strip (reads xp_b aliases) BEFORE gemm1 overwrites xp_b
    bcdt_gemm_kernel<<<320, 256, 0, stream>>>(hs_b, hs_lo, ws_hi, ws_lo,
                                              dtbi, bcr_f, dt_f);
    // GEMM1: M=8192 N=8192 K=2048 -> 32x32 tiles, XCD regions 16x8
    gemm_bt_8p<1, 32, 32, 4><<<dim3(1024), 512, 0, stream>>>(
        hs_b, w1_b, 32, 2048, 2048, z_b, xp_b, nullptr, 0);
    conv_x_kernel<<<dim3(16, 4096, 2), 256, 0, stream>>>(xp_b, cw, cbias, xq_b);
    conv_bc_kernel<<<dim3(1, 4096, 2), 256, 0, stream>>>(bcr_f, cw, cbias, bcc_f);
    cumsum_kernel<<<dim3(64, 16, 2), 256, 0, stream>>>(dt_f, alog, acs_f, cd_f);
    chunk_state_kernel<<<dim3(64, 16, 2), 256, 0, stream>>>(xq_b, bcc_f, dt_f, acs_f, cs_f);
    scan_kernel<<<dim3(64, 2), 256, 0, stream>>>(cs_f, cd_f);
    cb_kernel<<<dim3(6, 16, 2), 256, 0, stream>>>(bcc_f, cbt_f);
    ssd_y_kernel<<<dim3(64, 32, 2), 128, 0, stream>>>(xq_b, bcc_f, dt_f, acs_f, cbt_f, cs_f, Dv);
    cast_bf16_kernel<<<4096, 256, 0, stream>>>(wo, wo_b);   // 2048*4096
    rmsnorm_kernel<<<8192, 256, 0, stream>>>(xq_b, z_b, nw);
    // GEMM2: M=8192 N=2048 K=4096 -> 32x8 tiles, XCD regions 4x8
    gemm_bt_8p<2, 32, 8, 1><<<dim3(256), 512, 0, stream>>>(
        xq_b, wo_b, 64, 4096, 4096, nullptr, nullptr, out, 2048);
}